// Round 14
// baseline (356.609 us; speedup 1.0000x reference)
//
#include <hip/hip_runtime.h>

#define NN 50000
#define NE 400000
#define NG 256
#define BN_EPS 1e-5f
#define SCAN_E 8
#define SCAN_CHUNK 2048           // 256 threads * 8
#define SCAN_NB 25                // ceil(50000/2048)
#define KSPLIT 320                // conv1 split-K boundary (multiple of 64)

// packed weight-split region offsets (per plane, bf16 elements)
#define WOFF_C1W1 0               // 128*576
#define WOFF_C2W1 73728           // 128*128
#define WOFF_C3W1 90112
#define WOFF_W2_1 106496
#define WOFF_W2_2 122880
#define WOFF_W2_3 139264
#define WTOTAL    155648

typedef __attribute__((ext_vector_type(4))) float f32x4;
typedef __bf16 bf16x8 __attribute__((ext_vector_type(8)));
typedef __bf16 bf16x4 __attribute__((ext_vector_type(4)));

__device__ __forceinline__ void mfma_bf16(f32x4& d, bf16x8 a, bf16x8 b) {
  asm volatile("v_mfma_f32_16x16x32_bf16 %0, %1, %2, %0" : "+v"(d) : "v"(a), "v"(b));
}

// ---- all-W pre-split in one launch: wh/wl[n][k] = bf16 hi/lo of W[k][n] ----
__global__ __launch_bounds__(256)
void wprep_all(const float* __restrict__ w10, const float* __restrict__ w11,
               const float* __restrict__ w12, const float* __restrict__ w20,
               const float* __restrict__ w21, const float* __restrict__ w22,
               __bf16* __restrict__ wh, __bf16* __restrict__ wl) {
  int idx = blockIdx.x * 256 + threadIdx.x;
  if (idx >= WTOTAL) return;
  const float* W; int K, Kpad, base;
  if (idx < WOFF_C2W1)      { W = w10; K = 513; Kpad = 576; base = WOFF_C1W1; }
  else if (idx < WOFF_C3W1) { W = w11; K = 128; Kpad = 128; base = WOFF_C2W1; }
  else if (idx < WOFF_W2_1) { W = w12; K = 128; Kpad = 128; base = WOFF_C3W1; }
  else if (idx < WOFF_W2_2) { W = w20; K = 128; Kpad = 128; base = WOFF_W2_1; }
  else if (idx < WOFF_W2_3) { W = w21; K = 128; Kpad = 128; base = WOFF_W2_2; }
  else                      { W = w22; K = 128; Kpad = 128; base = WOFF_W2_3; }
  int local = idx - base;
  int n = local & 127, k = local >> 7;
  float v = (k < K) ? W[(long)k * 128 + n] : 0.f;
  __bf16 h = (__bf16)v;
  wh[base + (long)n * Kpad + k] = h;
  wl[base + (long)n * Kpad + k] = (__bf16)(v - (float)h);
}

// ---- all-BN fold in one launch: scale/shift[layer*128 + c] ----------------
__global__ void bn_prep_all(
    const float* __restrict__ b10, const float* __restrict__ g0,
    const float* __restrict__ bb0, const float* __restrict__ m0, const float* __restrict__ v0,
    const float* __restrict__ b11, const float* __restrict__ g1,
    const float* __restrict__ bb1, const float* __restrict__ m1, const float* __restrict__ v1,
    const float* __restrict__ b12, const float* __restrict__ g2,
    const float* __restrict__ bb2, const float* __restrict__ m2, const float* __restrict__ v2,
    float* __restrict__ scale, float* __restrict__ shift) {
  int t = threadIdx.x;           // 384 threads: layer = t>>7, c = t&127
  int layer = t >> 7, c = t & 127;
  const float* b1 = layer == 0 ? b10 : layer == 1 ? b11 : b12;
  const float* g  = layer == 0 ? g0  : layer == 1 ? g1  : g2;
  const float* bb = layer == 0 ? bb0 : layer == 1 ? bb1 : bb2;
  const float* m  = layer == 0 ? m0  : layer == 1 ? m1  : m2;
  const float* v  = layer == 0 ? v0  : layer == 1 ? v1  : v2;
  float s = g[c] * rsqrtf(v[c] + BN_EPS);
  scale[t] = s;
  shift[t] = (b1[c] - m[c]) * s + bb[c];
}

// ---- conv1 streaming GEMM, split-K over blockIdx.y ------------------------
// Inner structure VERBATIM from proven R7/R10/R12 gemm_ws; only the K-loop
// bounds come from blockIdx.y: half0 = [0,KSPLIT), half1 = [KSPLIT,Kpad).
// Each half writes an fp32 partial (proven OUT_SPLIT=false epilogue path)
// at Cf + blockIdx.y * M*128 (partials are contiguous by construction).
template<bool BIAS, bool RELU, bool OUT_SPLIT, bool A_FP32>
__global__ __launch_bounds__(256, 3)
void gemm_ws(const float* __restrict__ Af,
             const __bf16* __restrict__ Ah, const __bf16* __restrict__ Al,
             const __bf16* __restrict__ Wh, const __bf16* __restrict__ Wl,
             const float* __restrict__ bias, float* __restrict__ Cf,
             __bf16* __restrict__ Ch, __bf16* __restrict__ Cl,
             int M, int Kact, int Kpad) {
  __shared__ __align__(16) __bf16 bsh[128 * 64];   // [col][64k] swizzled octs
  __shared__ __align__(16) __bf16 bsl[128 * 64];
  const int t = threadIdx.x;
  const int wave = t >> 6, lane = t & 63;
  const int lr = lane & 15, kg = lane >> 4;
  const int r0 = blockIdx.x * 128 + wave * 32;
  const int kBeg = blockIdx.y ? KSPLIT : 0;
  const int kEnd = blockIdx.y ? Kpad : (gridDim.y > 1 ? KSPLIT : Kpad);
  float* Cfp = Cf + (long)blockIdx.y * (long)M * 128;

  bool okA[2];
  const float* apf[2];
  const __bf16 *aph[2], *apl[2];
#pragma unroll
  for (int mi = 0; mi < 2; ++mi) {
    int row = r0 + mi * 16 + lr;
    okA[mi] = row < M;
    long ro = okA[mi] ? (long)row : 0;
    if (A_FP32) { apf[mi] = Af + ro * Kact + kg * 8; aph[mi] = nullptr; apl[mi] = nullptr; }
    else { aph[mi] = Ah + ro * Kpad + kg * 8; apl[mi] = Al + ro * Kpad + kg * 8; apf[mi] = nullptr; }
  }

  f32x4 acc[2][8] = {};
  bf16x8 zero8;
#pragma unroll
  for (int j = 0; j < 8; ++j) zero8[j] = (__bf16)0.f;

  float f0[2][8], f1[2][8];                 // fp32 prefetch banks
  bf16x8 a0h[2], a0l[2], a1h[2], a1l[2];    // bf16 prefetch banks

#define PF(F, AH, AL, KQ)                                                     \
  if (A_FP32) {                                                               \
    if ((KQ) + 32 <= Kact) {                                                  \
      _Pragma("unroll") for (int mi = 0; mi < 2; ++mi)                        \
      _Pragma("unroll") for (int j = 0; j < 8; ++j)                           \
        F[mi][j] = okA[mi] ? apf[mi][(KQ) + j] : 0.f;                         \
    } else {                                                                  \
      _Pragma("unroll") for (int mi = 0; mi < 2; ++mi)                        \
      _Pragma("unroll") for (int j = 0; j < 8; ++j) {                         \
        int k = (KQ) + kg * 8 + j;                                            \
        F[mi][j] = (okA[mi] && k < Kact) ? apf[mi][(KQ) + j] : 0.f;           \
      }                                                                       \
    }                                                                         \
  } else {                                                                    \
    _Pragma("unroll") for (int mi = 0; mi < 2; ++mi) {                        \
      AH[mi] = okA[mi] ? *(const bf16x8*)(aph[mi] + (KQ)) : zero8;            \
      AL[mi] = okA[mi] ? *(const bf16x8*)(apl[mi] + (KQ)) : zero8;            \
    }                                                                         \
  }

#define STEP(F, AH, AL, S)                                                    \
  {                                                                           \
    bf16x8 fah[2], fal[2];                                                    \
    if (A_FP32) {                                                             \
      _Pragma("unroll") for (int mi = 0; mi < 2; ++mi)                        \
      _Pragma("unroll") for (int j = 0; j < 8; ++j) {                         \
        __bf16 h = (__bf16)F[mi][j];                                          \
        fah[mi][j] = h; fal[mi][j] = (__bf16)(F[mi][j] - (float)h);           \
      }                                                                       \
    } else {                                                                  \
      _Pragma("unroll") for (int mi = 0; mi < 2; ++mi) {                      \
        fah[mi] = AH[mi]; fal[mi] = AL[mi];                                   \
      }                                                                       \
    }                                                                         \
    _Pragma("unroll") for (int ni = 0; ni < 8; ++ni) {                        \
      int col = ni * 16 + lr;                                                 \
      int po = ((S) * 4 + kg) ^ (lr & 7);                                     \
      bf16x8 fbh = *(const bf16x8*)&bsh[col * 64 + po * 8];                   \
      bf16x8 fbl = *(const bf16x8*)&bsl[col * 64 + po * 8];                   \
      _Pragma("unroll") for (int mi = 0; mi < 2; ++mi)                        \
        mfma_bf16(acc[mi][ni], fah[mi], fbh);                                 \
      _Pragma("unroll") for (int mi = 0; mi < 2; ++mi)                        \
        mfma_bf16(acc[mi][ni], fal[mi], fbh);                                 \
      _Pragma("unroll") for (int mi = 0; mi < 2; ++mi)                        \
        mfma_bf16(acc[mi][ni], fah[mi], fbl);                                 \
    }                                                                         \
  }

  PF(f0, a0h, a0l, kBeg);
  for (int kc0 = kBeg; kc0 < kEnd; kc0 += 64) {
    __syncthreads();
    // stage W chunk (both planes), XOR-swizzled oct placement
#pragma unroll
    for (int i = 0; i < 4; ++i) {
      int id = t + i * 256;
      int col = id >> 3, oct = id & 7;
      int po = oct ^ (col & 7);
      *(bf16x8*)&bsh[col * 64 + po * 8] =
          *(const bf16x8*)&Wh[(long)col * Kpad + kc0 + oct * 8];
      *(bf16x8*)&bsl[col * 64 + po * 8] =
          *(const bf16x8*)&Wl[(long)col * Kpad + kc0 + oct * 8];
    }
    __syncthreads();
    PF(f1, a1h, a1l, kc0 + 32);          // overlaps step-0 MFMAs
    STEP(f0, a0h, a0l, 0);
    if (kc0 + 64 < kEnd) { PF(f0, a0h, a0l, kc0 + 64); }  // overlaps step-1
    STEP(f1, a1h, a1l, 1);
  }
#undef PF
#undef STEP

  // epilogue: C/D layout col=lane&15, row=(lane>>4)*4+reg
#pragma unroll
  for (int mi = 0; mi < 2; ++mi) {
#pragma unroll
    for (int ni = 0; ni < 8; ++ni) {
      int col = ni * 16 + lr;
      float bv = BIAS ? bias[col] : 0.f;
#pragma unroll
      for (int r = 0; r < 4; ++r) {
        int row = r0 + mi * 16 + kg * 4 + r;
        if (row < M) {
          float v = acc[mi][ni][r] + bv;
          if (RELU) v = fmaxf(v, 0.f);
          if (OUT_SPLIT) {
            __bf16 h = (__bf16)v;
            Ch[(long)row * 128 + col] = h;
            Cl[(long)row * 128 + col] = (__bf16)(v - (float)h);
          } else {
            Cfp[(long)row * 128 + col] = v;
          }
        }
      }
    }
  }
}

// ---- combine split-K partials and emit hi/lo bf16 planes ------------------
__global__ __launch_bounds__(256)
void combine_split(const float* __restrict__ y0, const float* __restrict__ y1,
                   __bf16* __restrict__ yh, __bf16* __restrict__ yl, int n4) {
  int i = blockIdx.x * 256 + threadIdx.x;
  if (i >= n4) return;
  float4 a = ((const float4*)y0)[i];
  float4 b = ((const float4*)y1)[i];
  float s0 = a.x + b.x, s1 = a.y + b.y, s2 = a.z + b.z, s3 = a.w + b.w;
  __bf16 h0 = (__bf16)s0, h1 = (__bf16)s1, h2 = (__bf16)s2, h3 = (__bf16)s3;
  bf16x4 hv, lv;
  hv[0] = h0; hv[1] = h1; hv[2] = h2; hv[3] = h3;
  lv[0] = (__bf16)(s0 - (float)h0); lv[1] = (__bf16)(s1 - (float)h1);
  lv[2] = (__bf16)(s2 - (float)h2); lv[3] = (__bf16)(s3 - (float)h3);
  *(bf16x4*)&yh[(long)i * 4] = hv;
  *(bf16x4*)&yl[(long)i * 4] = lv;
}

// ---- MFMA GEMM on pre-split bf16 — VERBATIM (proven R5/R10/R12) -----------
template<bool BIAS, bool RELU, bool OUT_SPLIT, bool A_FP32>
__global__ __launch_bounds__(512)
void gemm_bsp(const float* __restrict__ Af,
              const __bf16* __restrict__ Ah, const __bf16* __restrict__ Al,
              const __bf16* __restrict__ Wh, const __bf16* __restrict__ Wl,
              const float* __restrict__ bias, float* __restrict__ Cf,
              __bf16* __restrict__ Ch, __bf16* __restrict__ Cl,
              int M, int Kact, int Kpad) {
  __shared__ __align__(16) __bf16 ah[64 * 40];
  __shared__ __align__(16) __bf16 al[64 * 40];
  __shared__ __align__(16) __bf16 bh[128 * 40];
  __shared__ __align__(16) __bf16 bl[128 * 40];
  const int t = threadIdx.x;
  const int row0 = blockIdx.x * 64;
  const int wave = t >> 6, lane = t & 63;
  const int wr = wave >> 2, wc = wave & 3;   // 2x4 wave grid -> 32x32 tiles
  const int lr = lane & 15, kg = lane >> 4;

  // B staging: 128 rows x 4 k-octs, both planes per thread
  const int b_r = (t >> 2) & 127, b_ko = t & 3;
  const __bf16* bh_src = Wh + (long)b_r * Kpad + b_ko * 8;
  const __bf16* bl_src = Wl + (long)b_r * Kpad + b_ko * 8;
  __bf16* bh_dst = bh + b_r * 40 + b_ko * 8;
  __bf16* bl_dst = bl + b_r * 40 + b_ko * 8;

  f32x4 acc[2][2] = {};
  bf16x8 zero8;
#pragma unroll
  for (int j = 0; j < 8; ++j) zero8[j] = (__bf16)0.f;

  // plane path: 512 chunks = 2 planes x 64 rows x 4 k-octs
  const int a_pl = t >> 8, a_r8 = (t >> 2) & 63, a_ko = t & 3;
  const __bf16* a_src = (a_pl ? Al : Ah) + (long)(row0 + a_r8) * Kpad + a_ko * 8;
  __bf16* a_dst = (a_pl ? al : ah) + a_r8 * 40 + a_ko * 8;
  const bool a_ok8 = (row0 + a_r8) < M;
  // fp32 path: 64 rows x 8 k-quads(4 floats)
  const int a_rf = t >> 3, a_kq = t & 7;
  const bool a_okf = (row0 + a_rf) < M;
  const float* af_src = Af + (long)(row0 + a_rf) * Kact + a_kq * 4;
  __bf16* ahf_dst = ah + a_rf * 40 + a_kq * 4;
  __bf16* alf_dst = al + a_rf * 40 + a_kq * 4;

  bf16x8 av;
  float fa[4];
  if (A_FP32) {
#pragma unroll
    for (int j = 0; j < 4; ++j) {
      int k = a_kq * 4 + j;
      fa[j] = (a_okf && k < Kact) ? af_src[j] : 0.f;
    }
  } else {
    av = a_ok8 ? *(const bf16x8*)a_src : zero8;
  }
  bf16x8 bv0 = *(const bf16x8*)bh_src;
  bf16x8 bv1 = *(const bf16x8*)bl_src;

  for (int k0 = 0; k0 < Kpad; k0 += 32) {
    __syncthreads();
    if (A_FP32) {
      bf16x4 hv, lv;
#pragma unroll
      for (int j = 0; j < 4; ++j) {
        __bf16 h = (__bf16)fa[j];
        hv[j] = h; lv[j] = (__bf16)(fa[j] - (float)h);
      }
      *(bf16x4*)ahf_dst = hv;
      *(bf16x4*)alf_dst = lv;
    } else {
      *(bf16x8*)a_dst = av;
    }
    *(bf16x8*)bh_dst = bv0;
    *(bf16x8*)bl_dst = bv1;
    __syncthreads();
    int k1 = k0 + 32;
    if (k1 < Kpad) {            // prefetch next tile; overlaps MFMA below
      if (A_FP32) {
#pragma unroll
        for (int j = 0; j < 4; ++j) {
          int k = k1 + a_kq * 4 + j;
          fa[j] = (a_okf && k < Kact) ? af_src[k1 + j] : 0.f;
        }
      } else {
        av = a_ok8 ? *(const bf16x8*)(a_src + k1) : zero8;
      }
      bv0 = *(const bf16x8*)(bh_src + k1);
      bv1 = *(const bf16x8*)(bl_src + k1);
    }
    bf16x8 fah[2], fal[2], fbh[2], fbl[2];
#pragma unroll
    for (int mi = 0; mi < 2; ++mi) {
      int r = wr * 32 + mi * 16 + lr;
      fah[mi] = *(const bf16x8*)&ah[r * 40 + kg * 8];
      fal[mi] = *(const bf16x8*)&al[r * 40 + kg * 8];
    }
#pragma unroll
    for (int ni = 0; ni < 2; ++ni) {
      int c = wc * 32 + ni * 16 + lr;
      fbh[ni] = *(const bf16x8*)&bh[c * 40 + kg * 8];
      fbl[ni] = *(const bf16x8*)&bl[c * 40 + kg * 8];
    }
#pragma unroll
    for (int mi = 0; mi < 2; ++mi)
#pragma unroll
      for (int ni = 0; ni < 2; ++ni) {
        mfma_bf16(acc[mi][ni], fah[mi], fbh[ni]);
        mfma_bf16(acc[mi][ni], fal[mi], fbh[ni]);
        mfma_bf16(acc[mi][ni], fah[mi], fbl[ni]);
      }
  }
  // epilogue: C/D layout col=lane&15, row=(lane>>4)*4+reg
#pragma unroll
  for (int mi = 0; mi < 2; ++mi) {
#pragma unroll
    for (int ni = 0; ni < 2; ++ni) {
      int col = wc * 32 + ni * 16 + lr;
      float bv = BIAS ? bias[col] : 0.f;
#pragma unroll
      for (int r = 0; r < 4; ++r) {
        int row = row0 + wr * 32 + mi * 16 + kg * 4 + r;
        if (row < M) {
          float v = acc[mi][ni][r] + bv;
          if (RELU) v = fmaxf(v, 0.f);
          if (OUT_SPLIT) {
            __bf16 h = (__bf16)v;
            Ch[(long)row * 128 + col] = h;
            Cl[(long)row * 128 + col] = (__bf16)(v - (float)h);
          } else {
            Cf[(long)row * 128 + col] = v;
          }
        }
      }
    }
  }
}

// ---------------- CSR build -------------------------------------------------
__global__ __launch_bounds__(256)
void deg_count(const int* __restrict__ dst, int* __restrict__ deg, int E) {
  int e = blockIdx.x * 256 + threadIdx.x;
  if (e < E) atomicAdd(&deg[dst[e]], 1);
}

__global__ __launch_bounds__(256)
void scan_sums(const int* __restrict__ deg, int* __restrict__ bsum) {
  __shared__ int sm[256];
  int base = blockIdx.x * SCAN_CHUNK + threadIdx.x * SCAN_E;
  int s = 0;
#pragma unroll
  for (int k = 0; k < SCAN_E; ++k) { int i = base + k; if (i < NN) s += deg[i]; }
  sm[threadIdx.x] = s; __syncthreads();
  for (int off = 128; off > 0; off >>= 1) {
    if (threadIdx.x < off) sm[threadIdx.x] += sm[threadIdx.x + off];
    __syncthreads();
  }
  if (threadIdx.x == 0) bsum[blockIdx.x] = sm[0];
}

__global__ void scan_offs(const int* __restrict__ bsum, int* __restrict__ boff,
                          int* __restrict__ rowptr) {
  if (threadIdx.x == 0) {
    int run = 0;
    for (int i = 0; i < SCAN_NB; ++i) { boff[i] = run; run += bsum[i]; }
    rowptr[NN] = run;
  }
}

__global__ __launch_bounds__(256)
void scan_final(const int* __restrict__ boff, int* __restrict__ rowptr,
                int* __restrict__ cursor) {
  __shared__ int sm[256];
  int t = threadIdx.x;
  int base = blockIdx.x * SCAN_CHUNK + t * SCAN_E;
  int v[SCAN_E]; int s = 0;
#pragma unroll
  for (int k = 0; k < SCAN_E; ++k) { int i = base + k; v[k] = (i < NN) ? rowptr[i] : 0; s += v[k]; }
  sm[t] = s; __syncthreads();
  for (int off = 1; off < 256; off <<= 1) {
    int val = sm[t]; int add = (t >= off) ? sm[t - off] : 0;
    __syncthreads();
    sm[t] = val + add;
    __syncthreads();
  }
  int excl = (t == 0 ? 0 : sm[t - 1]) + boff[blockIdx.x];
#pragma unroll
  for (int k = 0; k < SCAN_E; ++k) {
    int i = base + k;
    if (i < NN) { rowptr[i] = excl; cursor[i] = excl; }
    excl += v[k];
  }
}

__global__ __launch_bounds__(256)
void scatter_csr(const int* __restrict__ src, const int* __restrict__ dst,
                 int* __restrict__ cursor, int* __restrict__ csr_src, int E) {
  int e = blockIdx.x * 256 + threadIdx.x;
  if (e < E) {
    int d = dst[e];
    int pos = atomicAdd(&cursor[d], 1);
    csr_src[pos] = src[e];
  }
}

// ------- gather+sum over in-edges, fused BN+ReLU — VERBATIM R11/R12 --------
__global__ __launch_bounds__(256)
void gather_bn_split(const __bf16* __restrict__ yh, const __bf16* __restrict__ yl,
                     const int* __restrict__ rowptr,
                     const int* __restrict__ csr_src, const float* __restrict__ scale,
                     const float* __restrict__ shift, __bf16* __restrict__ oh,
                     __bf16* __restrict__ ol) {
  const int grp = threadIdx.x >> 5;
  const int lane = threadIdx.x & 31;
  const int node = blockIdx.x * 8 + grp;
  if (node >= NN) return;
  int s = rowptr[node], e = rowptr[node + 1];
  // self term: hi + lo (fp32-exact reconstruction)
  bf16x4 sh4 = *(const bf16x4*)&yh[(long)node * 128 + lane * 4];
  bf16x4 sl4 = *(const bf16x4*)&yl[(long)node * 128 + lane * 4];
  float a0 = (float)sh4[0] + (float)sl4[0];
  float a1 = (float)sh4[1] + (float)sl4[1];
  float a2 = (float)sh4[2] + (float)sl4[2];
  float a3 = (float)sh4[3] + (float)sl4[3];
  float b0 = 0.f, b1 = 0.f, b2 = 0.f, b3 = 0.f;
  int i = s;
  for (; i + 3 < e; i += 4) {
    int s0 = csr_src[i], s1 = csr_src[i + 1], s2 = csr_src[i + 2], s3 = csr_src[i + 3];
    bf16x4 v0 = *(const bf16x4*)&yh[(long)s0 * 128 + lane * 4];
    bf16x4 v1 = *(const bf16x4*)&yh[(long)s1 * 128 + lane * 4];
    bf16x4 v2 = *(const bf16x4*)&yh[(long)s2 * 128 + lane * 4];
    bf16x4 v3 = *(const bf16x4*)&yh[(long)s3 * 128 + lane * 4];
    a0 += (float)v0[0]; a1 += (float)v0[1]; a2 += (float)v0[2]; a3 += (float)v0[3];
    b0 += (float)v1[0]; b1 += (float)v1[1]; b2 += (float)v1[2]; b3 += (float)v1[3];
    a0 += (float)v2[0]; a1 += (float)v2[1]; a2 += (float)v2[2]; a3 += (float)v2[3];
    b0 += (float)v3[0]; b1 += (float)v3[1]; b2 += (float)v3[2]; b3 += (float)v3[3];
  }
  for (; i < e; ++i) {
    int sn = csr_src[i];
    bf16x4 v = *(const bf16x4*)&yh[(long)sn * 128 + lane * 4];
    a0 += (float)v[0]; a1 += (float)v[1]; a2 += (float)v[2]; a3 += (float)v[3];
  }
  a0 += b0; a1 += b1; a2 += b2; a3 += b3;
  float4 sc = ((const float4*)scale)[lane];
  float4 sh = ((const float4*)shift)[lane];
  float o0 = fmaxf(a0 * sc.x + sh.x, 0.f);
  float o1 = fmaxf(a1 * sc.y + sh.y, 0.f);
  float o2 = fmaxf(a2 * sc.z + sh.z, 0.f);
  float o3 = fmaxf(a3 * sc.w + sh.w, 0.f);
  __bf16 h0 = (__bf16)o0, h1 = (__bf16)o1, h2 = (__bf16)o2, h3 = (__bf16)o3;
  bf16x4 hv, lv;
  hv[0] = h0; hv[1] = h1; hv[2] = h2; hv[3] = h3;
  lv[0] = (__bf16)(o0 - (float)h0); lv[1] = (__bf16)(o1 - (float)h1);
  lv[2] = (__bf16)(o2 - (float)h2); lv[3] = (__bf16)(o3 - (float)h3);
  *(bf16x4*)&oh[(long)node * 128 + lane * 4] = hv;
  *(bf16x4*)&ol[(long)node * 128 + lane * 4] = lv;
}

// ---- pool with fused graph-bounds binary search; grid (NG, 3) -------------
__global__ __launch_bounds__(128)
void pool_mean_split(const __bf16* __restrict__ h0h, const __bf16* __restrict__ h0l,
                     const __bf16* __restrict__ h1h, const __bf16* __restrict__ h1l,
                     const __bf16* __restrict__ h2h, const __bf16* __restrict__ h2l,
                     const int* __restrict__ batch, float* __restrict__ pooled) {
  __shared__ int se[2];
  int layer = blockIdx.y;
  const __bf16* hh = (layer == 0) ? h0h : (layer == 1) ? h1h : h2h;
  const __bf16* hl = (layer == 0) ? h0l : (layer == 1) ? h1l : h2l;
  int g = blockIdx.x, c = threadIdx.x;
  if (threadIdx.x < 2) {
    int target = g + (int)threadIdx.x;   // lower bound of batch >= target
    int lo = 0, hi = NN;
    while (lo < hi) {
      int mid = (lo + hi) >> 1;
      if (batch[mid] < target) lo = mid + 1; else hi = mid;
    }
    se[threadIdx.x] = lo;
  }
  __syncthreads();
  int s = se[0], e = se[1];
  float a0 = 0.f, a1 = 0.f, a2 = 0.f, a3 = 0.f;
  int i = s;
  for (; i + 3 < e; i += 4) {
    a0 += (float)hh[(long)i * 128 + c] + (float)hl[(long)i * 128 + c];
    a1 += (float)hh[(long)(i + 1) * 128 + c] + (float)hl[(long)(i + 1) * 128 + c];
    a2 += (float)hh[(long)(i + 2) * 128 + c] + (float)hl[(long)(i + 2) * 128 + c];
    a3 += (float)hh[(long)(i + 3) * 128 + c] + (float)hl[(long)(i + 3) * 128 + c];
  }
  for (; i < e; ++i)
    a0 += (float)hh[(long)i * 128 + c] + (float)hl[(long)i * 128 + c];
  float acc = (a0 + a1) + (a2 + a3);
  pooled[g * 384 + layer * 128 + c] = acc / fmaxf((float)(e - s), 1.f);
}

__global__ __launch_bounds__(384)
void lin1_k(const float* __restrict__ pooled, const float* __restrict__ w,
            const float* __restrict__ b, float* __restrict__ z) {
  __shared__ float pr[384];
  int mrow = blockIdx.x, t = threadIdx.x;
  pr[t] = pooled[mrow * 384 + t];
  __syncthreads();
  float acc = b[t];
  for (int k = 0; k < 384; ++k) acc += pr[k] * w[k * 384 + t];
  z[mrow * 384 + t] = fmaxf(acc, 0.f);
}

__global__ __launch_bounds__(192)
void lin2_k(const float* __restrict__ z, const float* __restrict__ w,
            const float* __restrict__ b, float* __restrict__ out) {
  int idx = blockIdx.x * 192 + threadIdx.x;
  if (idx >= NG * 3) return;
  int mrow = idx / 3, j = idx % 3;
  float acc = b[j];
  for (int k = 0; k < 384; ++k) acc += z[mrow * 384 + k] * w[k * 3 + j];
  out[idx] = acc;
}

extern "C" void kernel_launch(void* const* d_in, const int* in_sizes, int n_in,
                              void* d_out, int out_size, void* d_ws, size_t ws_size,
                              hipStream_t stream) {
  const float* x = (const float*)d_in[0];
  const int* ei = (const int*)d_in[1];
  const int* batch = (const int*)d_in[2];
  const int* srcv = ei;
  const int* dstv = ei + NE;
  const float* cw1[3] = {(const float*)d_in[3], (const float*)d_in[11], (const float*)d_in[19]};
  const float* cb1[3] = {(const float*)d_in[4], (const float*)d_in[12], (const float*)d_in[20]};
  const float* cg[3]  = {(const float*)d_in[5], (const float*)d_in[13], (const float*)d_in[21]};
  const float* cbb[3] = {(const float*)d_in[6], (const float*)d_in[14], (const float*)d_in[22]};
  const float* cm[3]  = {(const float*)d_in[7], (const float*)d_in[15], (const float*)d_in[23]};
  const float* cv[3]  = {(const float*)d_in[8], (const float*)d_in[16], (const float*)d_in[24]};
  const float* cw2[3] = {(const float*)d_in[9], (const float*)d_in[17], (const float*)d_in[25]};
  const float* cb2[3] = {(const float*)d_in[10], (const float*)d_in[18], (const float*)d_in[26]};
  const float* lin1_w = (const float*)d_in[27];
  const float* lin1_b = (const float*)d_in[28];
  const float* lin2_w = (const float*)d_in[29];
  const float* lin2_b = (const float*)d_in[30];

  const size_t NNF = (size_t)NN * 128;        // 6.4M
  float* wsf = (float*)d_ws;
  __bf16* yh = (__bf16*)wsf;                   // y hi-plane, 6.4M bf16
  __bf16* yl = yh + NNF;                       // y lo-plane, 6.4M bf16
  __bf16* Xb = (__bf16*)(wsf + NNF);           // bf16 plane region (after y)
  __bf16* gh = Xb;                             // gather split out, 6.4M bf16
  __bf16* gl = Xb + (size_t)6400000;
  __bf16* hh[3], *hl[3];
  for (int c = 0; c < 3; ++c) {
    hh[c] = Xb + (size_t)12800000 + (size_t)c * 12800000;
    hl[c] = hh[c] + (size_t)6400000;
  }
  // conv1 split-K fp32 partials: alias onto h1/h2 plane regions, which are
  // dead during layer 0 (h1 written in layer 1, h2 in layer 2). hh[1] and
  // hh[2] regions are contiguous: y1 = y0 + NNF floats exactly.
  float* y0 = (float*)hh[1];                   // 6.4M f32 over hh[1]+hl[1]
  float* misc = wsf + NNF + (size_t)25600000;  // after plane region (51.2M bf16)
  float* pooled = misc;                        // 256*384
  float* z      = pooled + (size_t)NG * 384;
  float* scale  = z + (size_t)NG * 384;        // 384 (3 layers x 128)
  float* shift  = scale + 384;
  __bf16* whbuf = (__bf16*)(shift + 384);      // WTOTAL bf16 per plane
  __bf16* wlbuf = whbuf + (size_t)WTOTAL;
  int* rowptr   = (int*)(wlbuf + (size_t)WTOTAL);   // NN+1
  int* cursor   = rowptr + NN + 1;
  int* csr_src  = cursor + NN;
  int* bsum     = csr_src + NE;
  int* boff     = bsum + 32;

  // ---- build CSR (by dst) once ----
  hipMemsetAsync(rowptr, 0, (NN + 1) * sizeof(int), stream);
  deg_count<<<(NE + 255) / 256, 256, 0, stream>>>(dstv, rowptr, NE);
  scan_sums<<<SCAN_NB, 256, 0, stream>>>(rowptr, bsum);
  scan_offs<<<1, 64, 0, stream>>>(bsum, boff, rowptr);
  scan_final<<<SCAN_NB, 256, 0, stream>>>(boff, rowptr, cursor);
  scatter_csr<<<(NE + 255) / 256, 256, 0, stream>>>(srcv, dstv, cursor, csr_src, NE);

  // ---- pre-fold all weights & BN params (2 launches total) ----
  wprep_all<<<(WTOTAL + 255) / 256, 256, 0, stream>>>(
      cw1[0], cw1[1], cw1[2], cw2[0], cw2[1], cw2[2], whbuf, wlbuf);
  bn_prep_all<<<1, 384, 0, stream>>>(
      cb1[0], cg[0], cbb[0], cm[0], cv[0],
      cb1[1], cg[1], cbb[1], cm[1], cv[1],
      cb1[2], cg[2], cbb[2], cm[2], cv[2], scale, shift);

  const int w1off[3] = {WOFF_C1W1, WOFF_C2W1, WOFF_C3W1};
  const int w2off[3] = {WOFF_W2_1, WOFF_W2_2, WOFF_W2_3};
  const int ws_grid  = (NN + 127) / 128;       // 391
  const int bsp_grid = (NN + 63) / 64;         // 782
  const int n4 = NN * 32;
  for (int c = 0; c < 3; ++c) {
    const __bf16* w1h = whbuf + w1off[c];
    const __bf16* w1l = wlbuf + w1off[c];
    const __bf16* w2h = whbuf + w2off[c];
    const __bf16* w2l = wlbuf + w2off[c];
    if (c == 0) {
      // split-K conv1: blockIdx.y picks K-half; partials y0, y0+NNF
      gemm_ws<false, false, false, true><<<dim3(ws_grid, 2), 256, 0, stream>>>(
          x, nullptr, nullptr, w1h, w1l, nullptr, y0, nullptr, nullptr, NN, 513, 576);
      combine_split<<<(n4 + 255) / 256, 256, 0, stream>>>(y0, y0 + NNF, yh, yl, n4);
    } else {
      gemm_bsp<false, false, true, false><<<bsp_grid, 512, 0, stream>>>(
          nullptr, hh[c - 1], hl[c - 1], w1h, w1l, nullptr, nullptr, yh, yl, NN, 128, 128);
    }
    gather_bn_split<<<(NN + 7) / 8, 256, 0, stream>>>(
        yh, yl, rowptr, csr_src, scale + (size_t)c * 128, shift + (size_t)c * 128, gh, gl);
    gemm_bsp<true, true, true, false><<<bsp_grid, 512, 0, stream>>>(
        nullptr, gh, gl, w2h, w2l, cb2[c], nullptr, hh[c], hl[c], NN, 128, 128);
  }
  pool_mean_split<<<dim3(NG, 3), 128, 0, stream>>>(hh[0], hl[0], hh[1], hl[1], hh[2], hl[2],
                                                   batch, pooled);
  lin1_k<<<NG, 384, 0, stream>>>(pooled, lin1_w, lin1_b, z);
  lin2_k<<<4, 192, 0, stream>>>(z, lin2_w, lin2_b, (float*)d_out);
}

// Round 15
// 347.624 us; speedup vs baseline: 1.0258x; 1.0258x over previous
//
#include <hip/hip_runtime.h>

#define NN 50000
#define NE 400000
#define NG 256
#define BN_EPS 1e-5f
#define SCAN_E 8
#define SCAN_CHUNK 2048           // 256 threads * 8
#define SCAN_NB 25                // ceil(50000/2048)

// packed weight-split region offsets (per plane, bf16 elements)
#define WOFF_C1W1 0               // 128*576
#define WOFF_C2W1 73728           // 128*128
#define WOFF_C3W1 90112
#define WOFF_W2_1 106496
#define WOFF_W2_2 122880
#define WOFF_W2_3 139264
#define WTOTAL    155648

typedef __attribute__((ext_vector_type(4))) float f32x4;
typedef __bf16 bf16x8 __attribute__((ext_vector_type(8)));
typedef __bf16 bf16x4 __attribute__((ext_vector_type(4)));

__device__ __forceinline__ void mfma_bf16(f32x4& d, bf16x8 a, bf16x8 b) {
  asm volatile("v_mfma_f32_16x16x32_bf16 %0, %1, %2, %0" : "+v"(d) : "v"(a), "v"(b));
}

// ---- all-W pre-split in one launch: wh/wl[n][k] = bf16 hi/lo of W[k][n] ----
__global__ __launch_bounds__(256)
void wprep_all(const float* __restrict__ w10, const float* __restrict__ w11,
               const float* __restrict__ w12, const float* __restrict__ w20,
               const float* __restrict__ w21, const float* __restrict__ w22,
               __bf16* __restrict__ wh, __bf16* __restrict__ wl) {
  int idx = blockIdx.x * 256 + threadIdx.x;
  if (idx >= WTOTAL) return;
  const float* W; int K, Kpad, base;
  if (idx < WOFF_C2W1)      { W = w10; K = 513; Kpad = 576; base = WOFF_C1W1; }
  else if (idx < WOFF_C3W1) { W = w11; K = 128; Kpad = 128; base = WOFF_C2W1; }
  else if (idx < WOFF_W2_1) { W = w12; K = 128; Kpad = 128; base = WOFF_C3W1; }
  else if (idx < WOFF_W2_2) { W = w20; K = 128; Kpad = 128; base = WOFF_W2_1; }
  else if (idx < WOFF_W2_3) { W = w21; K = 128; Kpad = 128; base = WOFF_W2_2; }
  else                      { W = w22; K = 128; Kpad = 128; base = WOFF_W2_3; }
  int local = idx - base;
  int n = local & 127, k = local >> 7;
  float v = (k < K) ? W[(long)k * 128 + n] : 0.f;
  __bf16 h = (__bf16)v;
  wh[base + (long)n * Kpad + k] = h;
  wl[base + (long)n * Kpad + k] = (__bf16)(v - (float)h);
}

// ---- all-BN fold in one launch: scale/shift[layer*128 + c] ----------------
__global__ void bn_prep_all(
    const float* __restrict__ b10, const float* __restrict__ g0,
    const float* __restrict__ bb0, const float* __restrict__ m0, const float* __restrict__ v0,
    const float* __restrict__ b11, const float* __restrict__ g1,
    const float* __restrict__ bb1, const float* __restrict__ m1, const float* __restrict__ v1,
    const float* __restrict__ b12, const float* __restrict__ g2,
    const float* __restrict__ bb2, const float* __restrict__ m2, const float* __restrict__ v2,
    float* __restrict__ scale, float* __restrict__ shift) {
  int t = threadIdx.x;           // 384 threads: layer = t>>7, c = t&127
  int layer = t >> 7, c = t & 127;
  const float* b1 = layer == 0 ? b10 : layer == 1 ? b11 : b12;
  const float* g  = layer == 0 ? g0  : layer == 1 ? g1  : g2;
  const float* bb = layer == 0 ? bb0 : layer == 1 ? bb1 : bb2;
  const float* m  = layer == 0 ? m0  : layer == 1 ? m1  : m2;
  const float* v  = layer == 0 ? v0  : layer == 1 ? v1  : v2;
  float s = g[c] * rsqrtf(v[c] + BN_EPS);
  scale[t] = s;
  shift[t] = (b1[c] - m[c]) * s + bb[c];
}

// ---- conv1 streaming GEMM — VERBATIM (proven R7/R10/R12) ------------------
template<bool BIAS, bool RELU, bool OUT_SPLIT, bool A_FP32>
__global__ __launch_bounds__(256, 3)
void gemm_ws(const float* __restrict__ Af,
             const __bf16* __restrict__ Ah, const __bf16* __restrict__ Al,
             const __bf16* __restrict__ Wh, const __bf16* __restrict__ Wl,
             const float* __restrict__ bias, float* __restrict__ Cf,
             __bf16* __restrict__ Ch, __bf16* __restrict__ Cl,
             int M, int Kact, int Kpad) {
  __shared__ __align__(16) __bf16 bsh[128 * 64];   // [col][64k] swizzled octs
  __shared__ __align__(16) __bf16 bsl[128 * 64];
  const int t = threadIdx.x;
  const int wave = t >> 6, lane = t & 63;
  const int lr = lane & 15, kg = lane >> 4;
  const int r0 = blockIdx.x * 128 + wave * 32;

  bool okA[2];
  const float* apf[2];
  const __bf16 *aph[2], *apl[2];
#pragma unroll
  for (int mi = 0; mi < 2; ++mi) {
    int row = r0 + mi * 16 + lr;
    okA[mi] = row < M;
    long ro = okA[mi] ? (long)row : 0;
    if (A_FP32) { apf[mi] = Af + ro * Kact + kg * 8; aph[mi] = nullptr; apl[mi] = nullptr; }
    else { aph[mi] = Ah + ro * Kpad + kg * 8; apl[mi] = Al + ro * Kpad + kg * 8; apf[mi] = nullptr; }
  }

  f32x4 acc[2][8] = {};
  bf16x8 zero8;
#pragma unroll
  for (int j = 0; j < 8; ++j) zero8[j] = (__bf16)0.f;

  float f0[2][8], f1[2][8];                 // fp32 prefetch banks
  bf16x8 a0h[2], a0l[2], a1h[2], a1l[2];    // bf16 prefetch banks

#define PF(F, AH, AL, KQ)                                                     \
  if (A_FP32) {                                                               \
    if ((KQ) + 32 <= Kact) {                                                  \
      _Pragma("unroll") for (int mi = 0; mi < 2; ++mi)                        \
      _Pragma("unroll") for (int j = 0; j < 8; ++j)                           \
        F[mi][j] = okA[mi] ? apf[mi][(KQ) + j] : 0.f;                         \
    } else {                                                                  \
      _Pragma("unroll") for (int mi = 0; mi < 2; ++mi)                        \
      _Pragma("unroll") for (int j = 0; j < 8; ++j) {                         \
        int k = (KQ) + kg * 8 + j;                                            \
        F[mi][j] = (okA[mi] && k < Kact) ? apf[mi][(KQ) + j] : 0.f;           \
      }                                                                       \
    }                                                                         \
  } else {                                                                    \
    _Pragma("unroll") for (int mi = 0; mi < 2; ++mi) {                        \
      AH[mi] = okA[mi] ? *(const bf16x8*)(aph[mi] + (KQ)) : zero8;            \
      AL[mi] = okA[mi] ? *(const bf16x8*)(apl[mi] + (KQ)) : zero8;            \
    }                                                                         \
  }

#define STEP(F, AH, AL, S)                                                    \
  {                                                                           \
    bf16x8 fah[2], fal[2];                                                    \
    if (A_FP32) {                                                             \
      _Pragma("unroll") for (int mi = 0; mi < 2; ++mi)                        \
      _Pragma("unroll") for (int j = 0; j < 8; ++j) {                         \
        __bf16 h = (__bf16)F[mi][j];                                          \
        fah[mi][j] = h; fal[mi][j] = (__bf16)(F[mi][j] - (float)h);           \
      }                                                                       \
    } else {                                                                  \
      _Pragma("unroll") for (int mi = 0; mi < 2; ++mi) {                      \
        fah[mi] = AH[mi]; fal[mi] = AL[mi];                                   \
      }                                                                       \
    }                                                                         \
    _Pragma("unroll") for (int ni = 0; ni < 8; ++ni) {                        \
      int col = ni * 16 + lr;                                                 \
      int po = ((S) * 4 + kg) ^ (lr & 7);                                     \
      bf16x8 fbh = *(const bf16x8*)&bsh[col * 64 + po * 8];                   \
      bf16x8 fbl = *(const bf16x8*)&bsl[col * 64 + po * 8];                   \
      _Pragma("unroll") for (int mi = 0; mi < 2; ++mi)                        \
        mfma_bf16(acc[mi][ni], fah[mi], fbh);                                 \
      _Pragma("unroll") for (int mi = 0; mi < 2; ++mi)                        \
        mfma_bf16(acc[mi][ni], fal[mi], fbh);                                 \
      _Pragma("unroll") for (int mi = 0; mi < 2; ++mi)                        \
        mfma_bf16(acc[mi][ni], fah[mi], fbl);                                 \
    }                                                                         \
  }

  PF(f0, a0h, a0l, 0);
  for (int kc0 = 0; kc0 < Kpad; kc0 += 64) {
    __syncthreads();
    // stage W chunk (both planes), XOR-swizzled oct placement
#pragma unroll
    for (int i = 0; i < 4; ++i) {
      int id = t + i * 256;
      int col = id >> 3, oct = id & 7;
      int po = oct ^ (col & 7);
      *(bf16x8*)&bsh[col * 64 + po * 8] =
          *(const bf16x8*)&Wh[(long)col * Kpad + kc0 + oct * 8];
      *(bf16x8*)&bsl[col * 64 + po * 8] =
          *(const bf16x8*)&Wl[(long)col * Kpad + kc0 + oct * 8];
    }
    __syncthreads();
    PF(f1, a1h, a1l, kc0 + 32);          // overlaps step-0 MFMAs
    STEP(f0, a0h, a0l, 0);
    if (kc0 + 64 < Kpad) { PF(f0, a0h, a0l, kc0 + 64); }  // overlaps step-1
    STEP(f1, a1h, a1l, 1);
  }
#undef PF
#undef STEP

  // epilogue: C/D layout col=lane&15, row=(lane>>4)*4+reg
#pragma unroll
  for (int mi = 0; mi < 2; ++mi) {
#pragma unroll
    for (int ni = 0; ni < 8; ++ni) {
      int col = ni * 16 + lr;
      float bv = BIAS ? bias[col] : 0.f;
#pragma unroll
      for (int r = 0; r < 4; ++r) {
        int row = r0 + mi * 16 + kg * 4 + r;
        if (row < M) {
          float v = acc[mi][ni][r] + bv;
          if (RELU) v = fmaxf(v, 0.f);
          if (OUT_SPLIT) {
            __bf16 h = (__bf16)v;
            Ch[(long)row * 128 + col] = h;
            Cl[(long)row * 128 + col] = (__bf16)(v - (float)h);
          } else {
            Cf[(long)row * 128 + col] = v;
          }
        }
      }
    }
  }
}

// ---- MFMA GEMM on pre-split bf16 — VERBATIM (proven R5/R10/R12) -----------
template<bool BIAS, bool RELU, bool OUT_SPLIT, bool A_FP32>
__global__ __launch_bounds__(512)
void gemm_bsp(const float* __restrict__ Af,
              const __bf16* __restrict__ Ah, const __bf16* __restrict__ Al,
              const __bf16* __restrict__ Wh, const __bf16* __restrict__ Wl,
              const float* __restrict__ bias, float* __restrict__ Cf,
              __bf16* __restrict__ Ch, __bf16* __restrict__ Cl,
              int M, int Kact, int Kpad) {
  __shared__ __align__(16) __bf16 ah[64 * 40];
  __shared__ __align__(16) __bf16 al[64 * 40];
  __shared__ __align__(16) __bf16 bh[128 * 40];
  __shared__ __align__(16) __bf16 bl[128 * 40];
  const int t = threadIdx.x;
  const int row0 = blockIdx.x * 64;
  const int wave = t >> 6, lane = t & 63;
  const int wr = wave >> 2, wc = wave & 3;   // 2x4 wave grid -> 32x32 tiles
  const int lr = lane & 15, kg = lane >> 4;

  // B staging: 128 rows x 4 k-octs, both planes per thread
  const int b_r = (t >> 2) & 127, b_ko = t & 3;
  const __bf16* bh_src = Wh + (long)b_r * Kpad + b_ko * 8;
  const __bf16* bl_src = Wl + (long)b_r * Kpad + b_ko * 8;
  __bf16* bh_dst = bh + b_r * 40 + b_ko * 8;
  __bf16* bl_dst = bl + b_r * 40 + b_ko * 8;

  f32x4 acc[2][2] = {};
  bf16x8 zero8;
#pragma unroll
  for (int j = 0; j < 8; ++j) zero8[j] = (__bf16)0.f;

  // plane path: 512 chunks = 2 planes x 64 rows x 4 k-octs
  const int a_pl = t >> 8, a_r8 = (t >> 2) & 63, a_ko = t & 3;
  const __bf16* a_src = (a_pl ? Al : Ah) + (long)(row0 + a_r8) * Kpad + a_ko * 8;
  __bf16* a_dst = (a_pl ? al : ah) + a_r8 * 40 + a_ko * 8;
  const bool a_ok8 = (row0 + a_r8) < M;
  // fp32 path: 64 rows x 8 k-quads(4 floats)
  const int a_rf = t >> 3, a_kq = t & 7;
  const bool a_okf = (row0 + a_rf) < M;
  const float* af_src = Af + (long)(row0 + a_rf) * Kact + a_kq * 4;
  __bf16* ahf_dst = ah + a_rf * 40 + a_kq * 4;
  __bf16* alf_dst = al + a_rf * 40 + a_kq * 4;

  bf16x8 av;
  float fa[4];
  if (A_FP32) {
#pragma unroll
    for (int j = 0; j < 4; ++j) {
      int k = a_kq * 4 + j;
      fa[j] = (a_okf && k < Kact) ? af_src[j] : 0.f;
    }
  } else {
    av = a_ok8 ? *(const bf16x8*)a_src : zero8;
  }
  bf16x8 bv0 = *(const bf16x8*)bh_src;
  bf16x8 bv1 = *(const bf16x8*)bl_src;

  for (int k0 = 0; k0 < Kpad; k0 += 32) {
    __syncthreads();
    if (A_FP32) {
      bf16x4 hv, lv;
#pragma unroll
      for (int j = 0; j < 4; ++j) {
        __bf16 h = (__bf16)fa[j];
        hv[j] = h; lv[j] = (__bf16)(fa[j] - (float)h);
      }
      *(bf16x4*)ahf_dst = hv;
      *(bf16x4*)alf_dst = lv;
    } else {
      *(bf16x8*)a_dst = av;
    }
    *(bf16x8*)bh_dst = bv0;
    *(bf16x8*)bl_dst = bv1;
    __syncthreads();
    int k1 = k0 + 32;
    if (k1 < Kpad) {            // prefetch next tile; overlaps MFMA below
      if (A_FP32) {
#pragma unroll
        for (int j = 0; j < 4; ++j) {
          int k = k1 + a_kq * 4 + j;
          fa[j] = (a_okf && k < Kact) ? af_src[k1 + j] : 0.f;
        }
      } else {
        av = a_ok8 ? *(const bf16x8*)(a_src + k1) : zero8;
      }
      bv0 = *(const bf16x8*)(bh_src + k1);
      bv1 = *(const bf16x8*)(bl_src + k1);
    }
    bf16x8 fah[2], fal[2], fbh[2], fbl[2];
#pragma unroll
    for (int mi = 0; mi < 2; ++mi) {
      int r = wr * 32 + mi * 16 + lr;
      fah[mi] = *(const bf16x8*)&ah[r * 40 + kg * 8];
      fal[mi] = *(const bf16x8*)&al[r * 40 + kg * 8];
    }
#pragma unroll
    for (int ni = 0; ni < 2; ++ni) {
      int c = wc * 32 + ni * 16 + lr;
      fbh[ni] = *(const bf16x8*)&bh[c * 40 + kg * 8];
      fbl[ni] = *(const bf16x8*)&bl[c * 40 + kg * 8];
    }
#pragma unroll
    for (int mi = 0; mi < 2; ++mi)
#pragma unroll
      for (int ni = 0; ni < 2; ++ni) {
        mfma_bf16(acc[mi][ni], fah[mi], fbh[ni]);
        mfma_bf16(acc[mi][ni], fal[mi], fbh[ni]);
        mfma_bf16(acc[mi][ni], fah[mi], fbl[ni]);
      }
  }
  // epilogue: C/D layout col=lane&15, row=(lane>>4)*4+reg
#pragma unroll
  for (int mi = 0; mi < 2; ++mi) {
#pragma unroll
    for (int ni = 0; ni < 2; ++ni) {
      int col = wc * 32 + ni * 16 + lr;
      float bv = BIAS ? bias[col] : 0.f;
#pragma unroll
      for (int r = 0; r < 4; ++r) {
        int row = row0 + wr * 32 + mi * 16 + kg * 4 + r;
        if (row < M) {
          float v = acc[mi][ni][r] + bv;
          if (RELU) v = fmaxf(v, 0.f);
          if (OUT_SPLIT) {
            __bf16 h = (__bf16)v;
            Ch[(long)row * 128 + col] = h;
            Cl[(long)row * 128 + col] = (__bf16)(v - (float)h);
          } else {
            Cf[(long)row * 128 + col] = v;
          }
        }
      }
    }
  }
}

// ---------------- CSR build -------------------------------------------------
__global__ __launch_bounds__(256)
void deg_count(const int* __restrict__ dst, int* __restrict__ deg, int E) {
  int e = blockIdx.x * 256 + threadIdx.x;
  if (e < E) atomicAdd(&deg[dst[e]], 1);
}

__global__ __launch_bounds__(256)
void scan_sums(const int* __restrict__ deg, int* __restrict__ bsum) {
  __shared__ int sm[256];
  int base = blockIdx.x * SCAN_CHUNK + threadIdx.x * SCAN_E;
  int s = 0;
#pragma unroll
  for (int k = 0; k < SCAN_E; ++k) { int i = base + k; if (i < NN) s += deg[i]; }
  sm[threadIdx.x] = s; __syncthreads();
  for (int off = 128; off > 0; off >>= 1) {
    if (threadIdx.x < off) sm[threadIdx.x] += sm[threadIdx.x + off];
    __syncthreads();
  }
  if (threadIdx.x == 0) bsum[blockIdx.x] = sm[0];
}

__global__ void scan_offs(const int* __restrict__ bsum, int* __restrict__ boff,
                          int* __restrict__ rowptr) {
  if (threadIdx.x == 0) {
    int run = 0;
    for (int i = 0; i < SCAN_NB; ++i) { boff[i] = run; run += bsum[i]; }
    rowptr[NN] = run;
  }
}

__global__ __launch_bounds__(256)
void scan_final(const int* __restrict__ boff, int* __restrict__ rowptr,
                int* __restrict__ cursor) {
  __shared__ int sm[256];
  int t = threadIdx.x;
  int base = blockIdx.x * SCAN_CHUNK + t * SCAN_E;
  int v[SCAN_E]; int s = 0;
#pragma unroll
  for (int k = 0; k < SCAN_E; ++k) { int i = base + k; v[k] = (i < NN) ? rowptr[i] : 0; s += v[k]; }
  sm[t] = s; __syncthreads();
  for (int off = 1; off < 256; off <<= 1) {
    int val = sm[t]; int add = (t >= off) ? sm[t - off] : 0;
    __syncthreads();
    sm[t] = val + add;
    __syncthreads();
  }
  int excl = (t == 0 ? 0 : sm[t - 1]) + boff[blockIdx.x];
#pragma unroll
  for (int k = 0; k < SCAN_E; ++k) {
    int i = base + k;
    if (i < NN) { rowptr[i] = excl; cursor[i] = excl; }
    excl += v[k];
  }
}

__global__ __launch_bounds__(256)
void scatter_csr(const int* __restrict__ src, const int* __restrict__ dst,
                 int* __restrict__ cursor, int* __restrict__ csr_src, int E) {
  int e = blockIdx.x * 256 + threadIdx.x;
  if (e < E) {
    int d = dst[e];
    int pos = atomicAdd(&cursor[d], 1);
    csr_src[pos] = src[e];
  }
}

// ------- gather+sum over in-edges, fused BN+ReLU — VERBATIM R11/R12 --------
__global__ __launch_bounds__(256)
void gather_bn_split(const __bf16* __restrict__ yh, const __bf16* __restrict__ yl,
                     const int* __restrict__ rowptr,
                     const int* __restrict__ csr_src, const float* __restrict__ scale,
                     const float* __restrict__ shift, __bf16* __restrict__ oh,
                     __bf16* __restrict__ ol) {
  const int grp = threadIdx.x >> 5;
  const int lane = threadIdx.x & 31;
  const int node = blockIdx.x * 8 + grp;
  if (node >= NN) return;
  int s = rowptr[node], e = rowptr[node + 1];
  // self term: hi + lo (fp32-exact reconstruction)
  bf16x4 sh4 = *(const bf16x4*)&yh[(long)node * 128 + lane * 4];
  bf16x4 sl4 = *(const bf16x4*)&yl[(long)node * 128 + lane * 4];
  float a0 = (float)sh4[0] + (float)sl4[0];
  float a1 = (float)sh4[1] + (float)sl4[1];
  float a2 = (float)sh4[2] + (float)sl4[2];
  float a3 = (float)sh4[3] + (float)sl4[3];
  float b0 = 0.f, b1 = 0.f, b2 = 0.f, b3 = 0.f;
  int i = s;
  for (; i + 3 < e; i += 4) {
    int s0 = csr_src[i], s1 = csr_src[i + 1], s2 = csr_src[i + 2], s3 = csr_src[i + 3];
    bf16x4 v0 = *(const bf16x4*)&yh[(long)s0 * 128 + lane * 4];
    bf16x4 v1 = *(const bf16x4*)&yh[(long)s1 * 128 + lane * 4];
    bf16x4 v2 = *(const bf16x4*)&yh[(long)s2 * 128 + lane * 4];
    bf16x4 v3 = *(const bf16x4*)&yh[(long)s3 * 128 + lane * 4];
    a0 += (float)v0[0]; a1 += (float)v0[1]; a2 += (float)v0[2]; a3 += (float)v0[3];
    b0 += (float)v1[0]; b1 += (float)v1[1]; b2 += (float)v1[2]; b3 += (float)v1[3];
    a0 += (float)v2[0]; a1 += (float)v2[1]; a2 += (float)v2[2]; a3 += (float)v2[3];
    b0 += (float)v3[0]; b1 += (float)v3[1]; b2 += (float)v3[2]; b3 += (float)v3[3];
  }
  for (; i < e; ++i) {
    int sn = csr_src[i];
    bf16x4 v = *(const bf16x4*)&yh[(long)sn * 128 + lane * 4];
    a0 += (float)v[0]; a1 += (float)v[1]; a2 += (float)v[2]; a3 += (float)v[3];
  }
  a0 += b0; a1 += b1; a2 += b2; a3 += b3;
  float4 sc = ((const float4*)scale)[lane];
  float4 sh = ((const float4*)shift)[lane];
  float o0 = fmaxf(a0 * sc.x + sh.x, 0.f);
  float o1 = fmaxf(a1 * sc.y + sh.y, 0.f);
  float o2 = fmaxf(a2 * sc.z + sh.z, 0.f);
  float o3 = fmaxf(a3 * sc.w + sh.w, 0.f);
  __bf16 h0 = (__bf16)o0, h1 = (__bf16)o1, h2 = (__bf16)o2, h3 = (__bf16)o3;
  bf16x4 hv, lv;
  hv[0] = h0; hv[1] = h1; hv[2] = h2; hv[3] = h3;
  lv[0] = (__bf16)(o0 - (float)h0); lv[1] = (__bf16)(o1 - (float)h1);
  lv[2] = (__bf16)(o2 - (float)h2); lv[3] = (__bf16)(o3 - (float)h3);
  *(bf16x4*)&oh[(long)node * 128 + lane * 4] = hv;
  *(bf16x4*)&ol[(long)node * 128 + lane * 4] = lv;
}

// ---- pool with fused graph-bounds; hi-plane only (bf16 avg, err ~3e-4) ----
__global__ __launch_bounds__(128)
void pool_mean_split(const __bf16* __restrict__ h0h, const __bf16* __restrict__ h0l,
                     const __bf16* __restrict__ h1h, const __bf16* __restrict__ h1l,
                     const __bf16* __restrict__ h2h, const __bf16* __restrict__ h2l,
                     const int* __restrict__ batch, float* __restrict__ pooled) {
  __shared__ int se[2];
  int layer = blockIdx.y;
  const __bf16* hh = (layer == 0) ? h0h : (layer == 1) ? h1h : h2h;
  int g = blockIdx.x, c = threadIdx.x;
  if (threadIdx.x < 2) {
    int target = g + (int)threadIdx.x;   // lower bound of batch >= target
    int lo = 0, hi = NN;
    while (lo < hi) {
      int mid = (lo + hi) >> 1;
      if (batch[mid] < target) lo = mid + 1; else hi = mid;
    }
    se[threadIdx.x] = lo;
  }
  __syncthreads();
  int s = se[0], e = se[1];
  float a0 = 0.f, a1 = 0.f, a2 = 0.f, a3 = 0.f;
  int i = s;
  for (; i + 3 < e; i += 4) {
    a0 += (float)hh[(long)i * 128 + c];
    a1 += (float)hh[(long)(i + 1) * 128 + c];
    a2 += (float)hh[(long)(i + 2) * 128 + c];
    a3 += (float)hh[(long)(i + 3) * 128 + c];
  }
  for (; i < e; ++i)
    a0 += (float)hh[(long)i * 128 + c];
  float acc = (a0 + a1) + (a2 + a3);
  pooled[g * 384 + layer * 128 + c] = acc / fmaxf((float)(e - s), 1.f);
}

__global__ __launch_bounds__(384)
void lin1_k(const float* __restrict__ pooled, const float* __restrict__ w,
            const float* __restrict__ b, float* __restrict__ z) {
  __shared__ float pr[384];
  int mrow = blockIdx.x, t = threadIdx.x;
  pr[t] = pooled[mrow * 384 + t];
  __syncthreads();
  float acc = b[t];
  for (int k = 0; k < 384; ++k) acc += pr[k] * w[k * 384 + t];
  z[mrow * 384 + t] = fmaxf(acc, 0.f);
}

__global__ __launch_bounds__(192)
void lin2_k(const float* __restrict__ z, const float* __restrict__ w,
            const float* __restrict__ b, float* __restrict__ out) {
  int idx = blockIdx.x * 192 + threadIdx.x;
  if (idx >= NG * 3) return;
  int mrow = idx / 3, j = idx % 3;
  float acc = b[j];
  for (int k = 0; k < 384; ++k) acc += z[mrow * 384 + k] * w[k * 3 + j];
  out[idx] = acc;
}

extern "C" void kernel_launch(void* const* d_in, const int* in_sizes, int n_in,
                              void* d_out, int out_size, void* d_ws, size_t ws_size,
                              hipStream_t stream) {
  const float* x = (const float*)d_in[0];
  const int* ei = (const int*)d_in[1];
  const int* batch = (const int*)d_in[2];
  const int* srcv = ei;
  const int* dstv = ei + NE;
  const float* cw1[3] = {(const float*)d_in[3], (const float*)d_in[11], (const float*)d_in[19]};
  const float* cb1[3] = {(const float*)d_in[4], (const float*)d_in[12], (const float*)d_in[20]};
  const float* cg[3]  = {(const float*)d_in[5], (const float*)d_in[13], (const float*)d_in[21]};
  const float* cbb[3] = {(const float*)d_in[6], (const float*)d_in[14], (const float*)d_in[22]};
  const float* cm[3]  = {(const float*)d_in[7], (const float*)d_in[15], (const float*)d_in[23]};
  const float* cv[3]  = {(const float*)d_in[8], (const float*)d_in[16], (const float*)d_in[24]};
  const float* cw2[3] = {(const float*)d_in[9], (const float*)d_in[17], (const float*)d_in[25]};
  const float* cb2[3] = {(const float*)d_in[10], (const float*)d_in[18], (const float*)d_in[26]};
  const float* lin1_w = (const float*)d_in[27];
  const float* lin1_b = (const float*)d_in[28];
  const float* lin2_w = (const float*)d_in[29];
  const float* lin2_b = (const float*)d_in[30];

  const size_t NNF = (size_t)NN * 128;        // 6.4M
  float* wsf = (float*)d_ws;
  __bf16* yh = (__bf16*)wsf;                   // y hi-plane, 6.4M bf16
  __bf16* yl = yh + NNF;                       // y lo-plane, 6.4M bf16
  __bf16* Xb = (__bf16*)(wsf + NNF);           // bf16 plane region (after y)
  __bf16* gh = Xb;                             // gather split out, 6.4M bf16
  __bf16* gl = Xb + (size_t)6400000;
  __bf16* hh[3], *hl[3];
  for (int c = 0; c < 3; ++c) {
    hh[c] = Xb + (size_t)12800000 + (size_t)c * 12800000;
    hl[c] = hh[c] + (size_t)6400000;
  }
  float* misc = wsf + NNF + (size_t)25600000;  // after plane region (51.2M bf16)
  float* pooled = misc;                        // 256*384
  float* z      = pooled + (size_t)NG * 384;
  float* scale  = z + (size_t)NG * 384;        // 384 (3 layers x 128)
  float* shift  = scale + 384;
  __bf16* whbuf = (__bf16*)(shift + 384);      // WTOTAL bf16 per plane
  __bf16* wlbuf = whbuf + (size_t)WTOTAL;
  int* rowptr   = (int*)(wlbuf + (size_t)WTOTAL);   // NN+1
  int* cursor   = rowptr + NN + 1;
  int* csr_src  = cursor + NN;
  int* bsum     = csr_src + NE;
  int* boff     = bsum + 32;

  // ---- build CSR (by dst) once ----
  hipMemsetAsync(rowptr, 0, (NN + 1) * sizeof(int), stream);
  deg_count<<<(NE + 255) / 256, 256, 0, stream>>>(dstv, rowptr, NE);
  scan_sums<<<SCAN_NB, 256, 0, stream>>>(rowptr, bsum);
  scan_offs<<<1, 64, 0, stream>>>(bsum, boff, rowptr);
  scan_final<<<SCAN_NB, 256, 0, stream>>>(boff, rowptr, cursor);
  scatter_csr<<<(NE + 255) / 256, 256, 0, stream>>>(srcv, dstv, cursor, csr_src, NE);

  // ---- pre-fold all weights & BN params (2 launches total) ----
  wprep_all<<<(WTOTAL + 255) / 256, 256, 0, stream>>>(
      cw1[0], cw1[1], cw1[2], cw2[0], cw2[1], cw2[2], whbuf, wlbuf);
  bn_prep_all<<<1, 384, 0, stream>>>(
      cb1[0], cg[0], cbb[0], cm[0], cv[0],
      cb1[1], cg[1], cbb[1], cm[1], cv[1],
      cb1[2], cg[2], cbb[2], cm[2], cv[2], scale, shift);

  const int w1off[3] = {WOFF_C1W1, WOFF_C2W1, WOFF_C3W1};
  const int w2off[3] = {WOFF_W2_1, WOFF_W2_2, WOFF_W2_3};
  const int ws_grid  = (NN + 127) / 128;       // 391
  const int bsp_grid = (NN + 63) / 64;         // 782
  for (int c = 0; c < 3; ++c) {
    const __bf16* w1h = whbuf + w1off[c];
    const __bf16* w1l = wlbuf + w1off[c];
    const __bf16* w2h = whbuf + w2off[c];
    const __bf16* w2l = wlbuf + w2off[c];
    if (c == 0)
      gemm_ws<false, false, true, true><<<ws_grid, 256, 0, stream>>>(
          x, nullptr, nullptr, w1h, w1l, nullptr, nullptr, yh, yl, NN, 513, 576);
    else
      gemm_bsp<false, false, true, false><<<bsp_grid, 512, 0, stream>>>(
          nullptr, hh[c - 1], hl[c - 1], w1h, w1l, nullptr, nullptr, yh, yl, NN, 128, 128);
    gather_bn_split<<<(NN + 7) / 8, 256, 0, stream>>>(
        yh, yl, rowptr, csr_src, scale + (size_t)c * 128, shift + (size_t)c * 128, gh, gl);
    gemm_bsp<true, true, true, false><<<bsp_grid, 512, 0, stream>>>(
        nullptr, gh, gl, w2h, w2l, cb2[c], nullptr, hh[c], hl[c], NN, 128, 128);
  }
  pool_mean_split<<<dim3(NG, 3), 128, 0, stream>>>(hh[0], hl[0], hh[1], hl[1], hh[2], hl[2],
                                                   batch, pooled);
  lin1_k<<<NG, 384, 0, stream>>>(pooled, lin1_w, lin1_b, z);
  lin2_k<<<4, 192, 0, stream>>>(z, lin2_w, lin2_b, (float*)d_out);
}

// Round 16
// 328.601 us; speedup vs baseline: 1.0852x; 1.0579x over previous
//
#include <hip/hip_runtime.h>

#define NN 50000
#define NE 400000
#define NG 256
#define BN_EPS 1e-5f
#define SCAN_E 8
#define SCAN_CHUNK 2048           // 256 threads * 8
#define SCAN_NB 25                // ceil(50000/2048)

// packed weight-split region offsets (per plane, bf16 elements)
#define WOFF_C1W1 0               // 128*576
#define WOFF_C2W1 73728           // 128*128
#define WOFF_C3W1 90112
#define WOFF_W2_1 106496
#define WOFF_W2_2 122880
#define WOFF_W2_3 139264
#define WTOTAL    155648

typedef __attribute__((ext_vector_type(4))) float f32x4;
typedef __bf16 bf16x8 __attribute__((ext_vector_type(8)));
typedef __bf16 bf16x4 __attribute__((ext_vector_type(4)));

__device__ __forceinline__ void mfma_bf16(f32x4& d, bf16x8 a, bf16x8 b) {
  asm volatile("v_mfma_f32_16x16x32_bf16 %0, %1, %2, %0" : "+v"(d) : "v"(a), "v"(b));
}

// ---- all-W pre-split + BN fold in ONE launch ------------------------------
// blocks [0, nW) handle weight planes; the LAST block folds BN params.
__global__ __launch_bounds__(256)
void wprep_all(const float* __restrict__ w10, const float* __restrict__ w11,
               const float* __restrict__ w12, const float* __restrict__ w20,
               const float* __restrict__ w21, const float* __restrict__ w22,
               __bf16* __restrict__ wh, __bf16* __restrict__ wl,
               const float* __restrict__ b10, const float* __restrict__ g0,
               const float* __restrict__ bb0, const float* __restrict__ m0,
               const float* __restrict__ v0,
               const float* __restrict__ b11, const float* __restrict__ g1,
               const float* __restrict__ bb1, const float* __restrict__ m1,
               const float* __restrict__ v1,
               const float* __restrict__ b12, const float* __restrict__ g2,
               const float* __restrict__ bb2, const float* __restrict__ m2,
               const float* __restrict__ v2,
               float* __restrict__ scale, float* __restrict__ shift) {
  if (blockIdx.x == gridDim.x - 1) {
    for (int t = threadIdx.x; t < 384; t += 256) {
      int layer = t >> 7, c = t & 127;
      const float* b1 = layer == 0 ? b10 : layer == 1 ? b11 : b12;
      const float* g  = layer == 0 ? g0  : layer == 1 ? g1  : g2;
      const float* bb = layer == 0 ? bb0 : layer == 1 ? bb1 : bb2;
      const float* m  = layer == 0 ? m0  : layer == 1 ? m1  : m2;
      const float* v  = layer == 0 ? v0  : layer == 1 ? v1  : v2;
      float s = g[c] * rsqrtf(v[c] + BN_EPS);
      scale[t] = s;
      shift[t] = (b1[c] - m[c]) * s + bb[c];
    }
    return;
  }
  int idx = blockIdx.x * 256 + threadIdx.x;
  if (idx >= WTOTAL) return;
  const float* W; int K, Kpad, base;
  if (idx < WOFF_C2W1)      { W = w10; K = 513; Kpad = 576; base = WOFF_C1W1; }
  else if (idx < WOFF_C3W1) { W = w11; K = 128; Kpad = 128; base = WOFF_C2W1; }
  else if (idx < WOFF_W2_1) { W = w12; K = 128; Kpad = 128; base = WOFF_C3W1; }
  else if (idx < WOFF_W2_2) { W = w20; K = 128; Kpad = 128; base = WOFF_W2_1; }
  else if (idx < WOFF_W2_3) { W = w21; K = 128; Kpad = 128; base = WOFF_W2_2; }
  else                      { W = w22; K = 128; Kpad = 128; base = WOFF_W2_3; }
  int local = idx - base;
  int n = local & 127, k = local >> 7;
  float v = (k < K) ? W[(long)k * 128 + n] : 0.f;
  __bf16 h = (__bf16)v;
  wh[base + (long)n * Kpad + k] = h;
  wl[base + (long)n * Kpad + k] = (__bf16)(v - (float)h);
}

// ---- conv1 streaming GEMM — R7/R10/R12 structure; fp32 A full-chunk loads
// vectorized via alignment-agnostic memcpy (gfx950 unaligned dwordx4).
template<bool BIAS, bool RELU, bool OUT_SPLIT, bool A_FP32>
__global__ __launch_bounds__(256, 3)
void gemm_ws(const float* __restrict__ Af,
             const __bf16* __restrict__ Ah, const __bf16* __restrict__ Al,
             const __bf16* __restrict__ Wh, const __bf16* __restrict__ Wl,
             const float* __restrict__ bias, float* __restrict__ Cf,
             __bf16* __restrict__ Ch, __bf16* __restrict__ Cl,
             int M, int Kact, int Kpad) {
  __shared__ __align__(16) __bf16 bsh[128 * 64];   // [col][64k] swizzled octs
  __shared__ __align__(16) __bf16 bsl[128 * 64];
  const int t = threadIdx.x;
  const int wave = t >> 6, lane = t & 63;
  const int lr = lane & 15, kg = lane >> 4;
  const int r0 = blockIdx.x * 128 + wave * 32;

  bool okA[2];
  const float* apf[2];
  const __bf16 *aph[2], *apl[2];
#pragma unroll
  for (int mi = 0; mi < 2; ++mi) {
    int row = r0 + mi * 16 + lr;
    okA[mi] = row < M;
    long ro = okA[mi] ? (long)row : 0;
    if (A_FP32) { apf[mi] = Af + ro * Kact + kg * 8; aph[mi] = nullptr; apl[mi] = nullptr; }
    else { aph[mi] = Ah + ro * Kpad + kg * 8; apl[mi] = Al + ro * Kpad + kg * 8; apf[mi] = nullptr; }
  }

  f32x4 acc[2][8] = {};
  bf16x8 zero8;
#pragma unroll
  for (int j = 0; j < 8; ++j) zero8[j] = (__bf16)0.f;

  float f0[2][8], f1[2][8];                 // fp32 prefetch banks
  bf16x8 a0h[2], a0l[2], a1h[2], a1l[2];    // bf16 prefetch banks

#define PF(F, AH, AL, KQ)                                                     \
  if (A_FP32) {                                                               \
    if ((KQ) + 32 <= Kact) {                                                  \
      _Pragma("unroll") for (int mi = 0; mi < 2; ++mi) {                      \
        float tmp8[8];                                                        \
        __builtin_memcpy(&tmp8[0], apf[mi] + (KQ), 32);                       \
        _Pragma("unroll") for (int j = 0; j < 8; ++j)                         \
          F[mi][j] = okA[mi] ? tmp8[j] : 0.f;                                 \
      }                                                                       \
    } else {                                                                  \
      _Pragma("unroll") for (int mi = 0; mi < 2; ++mi)                        \
      _Pragma("unroll") for (int j = 0; j < 8; ++j) {                         \
        int k = (KQ) + kg * 8 + j;                                            \
        F[mi][j] = (okA[mi] && k < Kact) ? apf[mi][(KQ) + j] : 0.f;           \
      }                                                                       \
    }                                                                         \
  } else {                                                                    \
    _Pragma("unroll") for (int mi = 0; mi < 2; ++mi) {                        \
      AH[mi] = okA[mi] ? *(const bf16x8*)(aph[mi] + (KQ)) : zero8;            \
      AL[mi] = okA[mi] ? *(const bf16x8*)(apl[mi] + (KQ)) : zero8;            \
    }                                                                         \
  }

#define STEP(F, AH, AL, S)                                                    \
  {                                                                           \
    bf16x8 fah[2], fal[2];                                                    \
    if (A_FP32) {                                                             \
      _Pragma("unroll") for (int mi = 0; mi < 2; ++mi)                        \
      _Pragma("unroll") for (int j = 0; j < 8; ++j) {                         \
        __bf16 h = (__bf16)F[mi][j];                                          \
        fah[mi][j] = h; fal[mi][j] = (__bf16)(F[mi][j] - (float)h);           \
      }                                                                       \
    } else {                                                                  \
      _Pragma("unroll") for (int mi = 0; mi < 2; ++mi) {                      \
        fah[mi] = AH[mi]; fal[mi] = AL[mi];                                   \
      }                                                                       \
    }                                                                         \
    _Pragma("unroll") for (int ni = 0; ni < 8; ++ni) {                        \
      int col = ni * 16 + lr;                                                 \
      int po = ((S) * 4 + kg) ^ (lr & 7);                                     \
      bf16x8 fbh = *(const bf16x8*)&bsh[col * 64 + po * 8];                   \
      bf16x8 fbl = *(const bf16x8*)&bsl[col * 64 + po * 8];                   \
      _Pragma("unroll") for (int mi = 0; mi < 2; ++mi)                        \
        mfma_bf16(acc[mi][ni], fah[mi], fbh);                                 \
      _Pragma("unroll") for (int mi = 0; mi < 2; ++mi)                        \
        mfma_bf16(acc[mi][ni], fal[mi], fbh);                                 \
      _Pragma("unroll") for (int mi = 0; mi < 2; ++mi)                        \
        mfma_bf16(acc[mi][ni], fah[mi], fbl);                                 \
    }                                                                         \
  }

  PF(f0, a0h, a0l, 0);
  for (int kc0 = 0; kc0 < Kpad; kc0 += 64) {
    __syncthreads();
    // stage W chunk (both planes), XOR-swizzled oct placement
#pragma unroll
    for (int i = 0; i < 4; ++i) {
      int id = t + i * 256;
      int col = id >> 3, oct = id & 7;
      int po = oct ^ (col & 7);
      *(bf16x8*)&bsh[col * 64 + po * 8] =
          *(const bf16x8*)&Wh[(long)col * Kpad + kc0 + oct * 8];
      *(bf16x8*)&bsl[col * 64 + po * 8] =
          *(const bf16x8*)&Wl[(long)col * Kpad + kc0 + oct * 8];
    }
    __syncthreads();
    PF(f1, a1h, a1l, kc0 + 32);          // overlaps step-0 MFMAs
    STEP(f0, a0h, a0l, 0);
    if (kc0 + 64 < Kpad) { PF(f0, a0h, a0l, kc0 + 64); }  // overlaps step-1
    STEP(f1, a1h, a1l, 1);
  }
#undef PF
#undef STEP

  // epilogue: C/D layout col=lane&15, row=(lane>>4)*4+reg
#pragma unroll
  for (int mi = 0; mi < 2; ++mi) {
#pragma unroll
    for (int ni = 0; ni < 8; ++ni) {
      int col = ni * 16 + lr;
      float bv = BIAS ? bias[col] : 0.f;
#pragma unroll
      for (int r = 0; r < 4; ++r) {
        int row = r0 + mi * 16 + kg * 4 + r;
        if (row < M) {
          float v = acc[mi][ni][r] + bv;
          if (RELU) v = fmaxf(v, 0.f);
          if (OUT_SPLIT) {
            __bf16 h = (__bf16)v;
            Ch[(long)row * 128 + col] = h;
            Cl[(long)row * 128 + col] = (__bf16)(v - (float)h);
          } else {
            Cf[(long)row * 128 + col] = v;
          }
        }
      }
    }
  }
}

// ---- MFMA GEMM on pre-split bf16 — VERBATIM (proven R5/R10/R12) -----------
template<bool BIAS, bool RELU, bool OUT_SPLIT, bool A_FP32>
__global__ __launch_bounds__(512)
void gemm_bsp(const float* __restrict__ Af,
              const __bf16* __restrict__ Ah, const __bf16* __restrict__ Al,
              const __bf16* __restrict__ Wh, const __bf16* __restrict__ Wl,
              const float* __restrict__ bias, float* __restrict__ Cf,
              __bf16* __restrict__ Ch, __bf16* __restrict__ Cl,
              int M, int Kact, int Kpad) {
  __shared__ __align__(16) __bf16 ah[64 * 40];
  __shared__ __align__(16) __bf16 al[64 * 40];
  __shared__ __align__(16) __bf16 bh[128 * 40];
  __shared__ __align__(16) __bf16 bl[128 * 40];
  const int t = threadIdx.x;
  const int row0 = blockIdx.x * 64;
  const int wave = t >> 6, lane = t & 63;
  const int wr = wave >> 2, wc = wave & 3;   // 2x4 wave grid -> 32x32 tiles
  const int lr = lane & 15, kg = lane >> 4;

  // B staging: 128 rows x 4 k-octs, both planes per thread
  const int b_r = (t >> 2) & 127, b_ko = t & 3;
  const __bf16* bh_src = Wh + (long)b_r * Kpad + b_ko * 8;
  const __bf16* bl_src = Wl + (long)b_r * Kpad + b_ko * 8;
  __bf16* bh_dst = bh + b_r * 40 + b_ko * 8;
  __bf16* bl_dst = bl + b_r * 40 + b_ko * 8;

  f32x4 acc[2][2] = {};
  bf16x8 zero8;
#pragma unroll
  for (int j = 0; j < 8; ++j) zero8[j] = (__bf16)0.f;

  // plane path: 512 chunks = 2 planes x 64 rows x 4 k-octs
  const int a_pl = t >> 8, a_r8 = (t >> 2) & 63, a_ko = t & 3;
  const __bf16* a_src = (a_pl ? Al : Ah) + (long)(row0 + a_r8) * Kpad + a_ko * 8;
  __bf16* a_dst = (a_pl ? al : ah) + a_r8 * 40 + a_ko * 8;
  const bool a_ok8 = (row0 + a_r8) < M;
  // fp32 path: 64 rows x 8 k-quads(4 floats)
  const int a_rf = t >> 3, a_kq = t & 7;
  const bool a_okf = (row0 + a_rf) < M;
  const float* af_src = Af + (long)(row0 + a_rf) * Kact + a_kq * 4;
  __bf16* ahf_dst = ah + a_rf * 40 + a_kq * 4;
  __bf16* alf_dst = al + a_rf * 40 + a_kq * 4;

  bf16x8 av;
  float fa[4];
  if (A_FP32) {
#pragma unroll
    for (int j = 0; j < 4; ++j) {
      int k = a_kq * 4 + j;
      fa[j] = (a_okf && k < Kact) ? af_src[j] : 0.f;
    }
  } else {
    av = a_ok8 ? *(const bf16x8*)a_src : zero8;
  }
  bf16x8 bv0 = *(const bf16x8*)bh_src;
  bf16x8 bv1 = *(const bf16x8*)bl_src;

  for (int k0 = 0; k0 < Kpad; k0 += 32) {
    __syncthreads();
    if (A_FP32) {
      bf16x4 hv, lv;
#pragma unroll
      for (int j = 0; j < 4; ++j) {
        __bf16 h = (__bf16)fa[j];
        hv[j] = h; lv[j] = (__bf16)(fa[j] - (float)h);
      }
      *(bf16x4*)ahf_dst = hv;
      *(bf16x4*)alf_dst = lv;
    } else {
      *(bf16x8*)a_dst = av;
    }
    *(bf16x8*)bh_dst = bv0;
    *(bf16x8*)bl_dst = bv1;
    __syncthreads();
    int k1 = k0 + 32;
    if (k1 < Kpad) {            // prefetch next tile; overlaps MFMA below
      if (A_FP32) {
#pragma unroll
        for (int j = 0; j < 4; ++j) {
          int k = k1 + a_kq * 4 + j;
          fa[j] = (a_okf && k < Kact) ? af_src[k1 + j] : 0.f;
        }
      } else {
        av = a_ok8 ? *(const bf16x8*)(a_src + k1) : zero8;
      }
      bv0 = *(const bf16x8*)(bh_src + k1);
      bv1 = *(const bf16x8*)(bl_src + k1);
    }
    bf16x8 fah[2], fal[2], fbh[2], fbl[2];
#pragma unroll
    for (int mi = 0; mi < 2; ++mi) {
      int r = wr * 32 + mi * 16 + lr;
      fah[mi] = *(const bf16x8*)&ah[r * 40 + kg * 8];
      fal[mi] = *(const bf16x8*)&al[r * 40 + kg * 8];
    }
#pragma unroll
    for (int ni = 0; ni < 2; ++ni) {
      int c = wc * 32 + ni * 16 + lr;
      fbh[ni] = *(const bf16x8*)&bh[c * 40 + kg * 8];
      fbl[ni] = *(const bf16x8*)&bl[c * 40 + kg * 8];
    }
#pragma unroll
    for (int mi = 0; mi < 2; ++mi)
#pragma unroll
      for (int ni = 0; ni < 2; ++ni) {
        mfma_bf16(acc[mi][ni], fah[mi], fbh[ni]);
        mfma_bf16(acc[mi][ni], fal[mi], fbh[ni]);
        mfma_bf16(acc[mi][ni], fah[mi], fbl[ni]);
      }
  }
  // epilogue: C/D layout col=lane&15, row=(lane>>4)*4+reg
#pragma unroll
  for (int mi = 0; mi < 2; ++mi) {
#pragma unroll
    for (int ni = 0; ni < 2; ++ni) {
      int col = wc * 32 + ni * 16 + lr;
      float bv = BIAS ? bias[col] : 0.f;
#pragma unroll
      for (int r = 0; r < 4; ++r) {
        int row = row0 + wr * 32 + mi * 16 + kg * 4 + r;
        if (row < M) {
          float v = acc[mi][ni][r] + bv;
          if (RELU) v = fmaxf(v, 0.f);
          if (OUT_SPLIT) {
            __bf16 h = (__bf16)v;
            Ch[(long)row * 128 + col] = h;
            Cl[(long)row * 128 + col] = (__bf16)(v - (float)h);
          } else {
            Cf[(long)row * 128 + col] = v;
          }
        }
      }
    }
  }
}

// ---------------- CSR build -------------------------------------------------
__global__ __launch_bounds__(256)
void deg_count(const int* __restrict__ dst, int* __restrict__ deg, int E) {
  int e = blockIdx.x * 256 + threadIdx.x;
  if (e < E) atomicAdd(&deg[dst[e]], 1);
}

__global__ __launch_bounds__(256)
void scan_sums(const int* __restrict__ deg, int* __restrict__ bsum) {
  __shared__ int sm[256];
  int base = blockIdx.x * SCAN_CHUNK + threadIdx.x * SCAN_E;
  int s = 0;
#pragma unroll
  for (int k = 0; k < SCAN_E; ++k) { int i = base + k; if (i < NN) s += deg[i]; }
  sm[threadIdx.x] = s; __syncthreads();
  for (int off = 128; off > 0; off >>= 1) {
    if (threadIdx.x < off) sm[threadIdx.x] += sm[threadIdx.x + off];
    __syncthreads();
  }
  if (threadIdx.x == 0) bsum[blockIdx.x] = sm[0];
}

__global__ void scan_offs(const int* __restrict__ bsum, int* __restrict__ boff,
                          int* __restrict__ rowptr) {
  if (threadIdx.x == 0) {
    int run = 0;
    for (int i = 0; i < SCAN_NB; ++i) { boff[i] = run; run += bsum[i]; }
    rowptr[NN] = run;
  }
}

__global__ __launch_bounds__(256)
void scan_final(const int* __restrict__ boff, int* __restrict__ rowptr,
                int* __restrict__ cursor) {
  __shared__ int sm[256];
  int t = threadIdx.x;
  int base = blockIdx.x * SCAN_CHUNK + t * SCAN_E;
  int v[SCAN_E]; int s = 0;
#pragma unroll
  for (int k = 0; k < SCAN_E; ++k) { int i = base + k; v[k] = (i < NN) ? rowptr[i] : 0; s += v[k]; }
  sm[t] = s; __syncthreads();
  for (int off = 1; off < 256; off <<= 1) {
    int val = sm[t]; int add = (t >= off) ? sm[t - off] : 0;
    __syncthreads();
    sm[t] = val + add;
    __syncthreads();
  }
  int excl = (t == 0 ? 0 : sm[t - 1]) + boff[blockIdx.x];
#pragma unroll
  for (int k = 0; k < SCAN_E; ++k) {
    int i = base + k;
    if (i < NN) { rowptr[i] = excl; cursor[i] = excl; }
    excl += v[k];
  }
}

__global__ __launch_bounds__(256)
void scatter_csr(const int* __restrict__ src, const int* __restrict__ dst,
                 int* __restrict__ cursor, int* __restrict__ csr_src, int E) {
  int e = blockIdx.x * 256 + threadIdx.x;
  if (e < E) {
    int d = dst[e];
    int pos = atomicAdd(&cursor[d], 1);
    csr_src[pos] = src[e];
  }
}

// ------- gather+sum over in-edges, fused BN+ReLU — VERBATIM R11/R12 --------
__global__ __launch_bounds__(256)
void gather_bn_split(const __bf16* __restrict__ yh, const __bf16* __restrict__ yl,
                     const int* __restrict__ rowptr,
                     const int* __restrict__ csr_src, const float* __restrict__ scale,
                     const float* __restrict__ shift, __bf16* __restrict__ oh,
                     __bf16* __restrict__ ol) {
  const int grp = threadIdx.x >> 5;
  const int lane = threadIdx.x & 31;
  const int node = blockIdx.x * 8 + grp;
  if (node >= NN) return;
  int s = rowptr[node], e = rowptr[node + 1];
  // self term: hi + lo (fp32-exact reconstruction)
  bf16x4 sh4 = *(const bf16x4*)&yh[(long)node * 128 + lane * 4];
  bf16x4 sl4 = *(const bf16x4*)&yl[(long)node * 128 + lane * 4];
  float a0 = (float)sh4[0] + (float)sl4[0];
  float a1 = (float)sh4[1] + (float)sl4[1];
  float a2 = (float)sh4[2] + (float)sl4[2];
  float a3 = (float)sh4[3] + (float)sl4[3];
  float b0 = 0.f, b1 = 0.f, b2 = 0.f, b3 = 0.f;
  int i = s;
  for (; i + 3 < e; i += 4) {
    int s0 = csr_src[i], s1 = csr_src[i + 1], s2 = csr_src[i + 2], s3 = csr_src[i + 3];
    bf16x4 v0 = *(const bf16x4*)&yh[(long)s0 * 128 + lane * 4];
    bf16x4 v1 = *(const bf16x4*)&yh[(long)s1 * 128 + lane * 4];
    bf16x4 v2 = *(const bf16x4*)&yh[(long)s2 * 128 + lane * 4];
    bf16x4 v3 = *(const bf16x4*)&yh[(long)s3 * 128 + lane * 4];
    a0 += (float)v0[0]; a1 += (float)v0[1]; a2 += (float)v0[2]; a3 += (float)v0[3];
    b0 += (float)v1[0]; b1 += (float)v1[1]; b2 += (float)v1[2]; b3 += (float)v1[3];
    a0 += (float)v2[0]; a1 += (float)v2[1]; a2 += (float)v2[2]; a3 += (float)v2[3];
    b0 += (float)v3[0]; b1 += (float)v3[1]; b2 += (float)v3[2]; b3 += (float)v3[3];
  }
  for (; i < e; ++i) {
    int sn = csr_src[i];
    bf16x4 v = *(const bf16x4*)&yh[(long)sn * 128 + lane * 4];
    a0 += (float)v[0]; a1 += (float)v[1]; a2 += (float)v[2]; a3 += (float)v[3];
  }
  a0 += b0; a1 += b1; a2 += b2; a3 += b3;
  float4 sc = ((const float4*)scale)[lane];
  float4 sh = ((const float4*)shift)[lane];
  float o0 = fmaxf(a0 * sc.x + sh.x, 0.f);
  float o1 = fmaxf(a1 * sc.y + sh.y, 0.f);
  float o2 = fmaxf(a2 * sc.z + sh.z, 0.f);
  float o3 = fmaxf(a3 * sc.w + sh.w, 0.f);
  __bf16 h0 = (__bf16)o0, h1 = (__bf16)o1, h2 = (__bf16)o2, h3 = (__bf16)o3;
  bf16x4 hv, lv;
  hv[0] = h0; hv[1] = h1; hv[2] = h2; hv[3] = h3;
  lv[0] = (__bf16)(o0 - (float)h0); lv[1] = (__bf16)(o1 - (float)h1);
  lv[2] = (__bf16)(o2 - (float)h2); lv[3] = (__bf16)(o3 - (float)h3);
  *(bf16x4*)&oh[(long)node * 128 + lane * 4] = hv;
  *(bf16x4*)&ol[(long)node * 128 + lane * 4] = lv;
}

// ---- pool with fused graph-bounds; hi-plane only --------------------------
__global__ __launch_bounds__(128)
void pool_mean_split(const __bf16* __restrict__ h0h, const __bf16* __restrict__ h0l,
                     const __bf16* __restrict__ h1h, const __bf16* __restrict__ h1l,
                     const __bf16* __restrict__ h2h, const __bf16* __restrict__ h2l,
                     const int* __restrict__ batch, float* __restrict__ pooled) {
  __shared__ int se[2];
  int layer = blockIdx.y;
  const __bf16* hh = (layer == 0) ? h0h : (layer == 1) ? h1h : h2h;
  int g = blockIdx.x, c = threadIdx.x;
  if (threadIdx.x < 2) {
    int target = g + (int)threadIdx.x;   // lower bound of batch >= target
    int lo = 0, hi = NN;
    while (lo < hi) {
      int mid = (lo + hi) >> 1;
      if (batch[mid] < target) lo = mid + 1; else hi = mid;
    }
    se[threadIdx.x] = lo;
  }
  __syncthreads();
  int s = se[0], e = se[1];
  float a0 = 0.f, a1 = 0.f, a2 = 0.f, a3 = 0.f;
  int i = s;
  for (; i + 3 < e; i += 4) {
    a0 += (float)hh[(long)i * 128 + c];
    a1 += (float)hh[(long)(i + 1) * 128 + c];
    a2 += (float)hh[(long)(i + 2) * 128 + c];
    a3 += (float)hh[(long)(i + 3) * 128 + c];
  }
  for (; i < e; ++i)
    a0 += (float)hh[(long)i * 128 + c];
  float acc = (a0 + a1) + (a2 + a3);
  pooled[g * 384 + layer * 128 + c] = acc / fmaxf((float)(e - s), 1.f);
}

__global__ __launch_bounds__(384)
void lin1_k(const float* __restrict__ pooled, const float* __restrict__ w,
            const float* __restrict__ b, float* __restrict__ z) {
  __shared__ float pr[384];
  int mrow = blockIdx.x, t = threadIdx.x;
  pr[t] = pooled[mrow * 384 + t];
  __syncthreads();
  float acc = b[t];
  for (int k = 0; k < 384; ++k) acc += pr[k] * w[k * 384 + t];
  z[mrow * 384 + t] = fmaxf(acc, 0.f);
}

__global__ __launch_bounds__(192)
void lin2_k(const float* __restrict__ z, const float* __restrict__ w,
            const float* __restrict__ b, float* __restrict__ out) {
  int idx = blockIdx.x * 192 + threadIdx.x;
  if (idx >= NG * 3) return;
  int mrow = idx / 3, j = idx % 3;
  float acc = b[j];
  for (int k = 0; k < 384; ++k) acc += z[mrow * 384 + k] * w[k * 3 + j];
  out[idx] = acc;
}

extern "C" void kernel_launch(void* const* d_in, const int* in_sizes, int n_in,
                              void* d_out, int out_size, void* d_ws, size_t ws_size,
                              hipStream_t stream) {
  const float* x = (const float*)d_in[0];
  const int* ei = (const int*)d_in[1];
  const int* batch = (const int*)d_in[2];
  const int* srcv = ei;
  const int* dstv = ei + NE;
  const float* cw1[3] = {(const float*)d_in[3], (const float*)d_in[11], (const float*)d_in[19]};
  const float* cb1[3] = {(const float*)d_in[4], (const float*)d_in[12], (const float*)d_in[20]};
  const float* cg[3]  = {(const float*)d_in[5], (const float*)d_in[13], (const float*)d_in[21]};
  const float* cbb[3] = {(const float*)d_in[6], (const float*)d_in[14], (const float*)d_in[22]};
  const float* cm[3]  = {(const float*)d_in[7], (const float*)d_in[15], (const float*)d_in[23]};
  const float* cv[3]  = {(const float*)d_in[8], (const float*)d_in[16], (const float*)d_in[24]};
  const float* cw2[3] = {(const float*)d_in[9], (const float*)d_in[17], (const float*)d_in[25]};
  const float* cb2[3] = {(const float*)d_in[10], (const float*)d_in[18], (const float*)d_in[26]};
  const float* lin1_w = (const float*)d_in[27];
  const float* lin1_b = (const float*)d_in[28];
  const float* lin2_w = (const float*)d_in[29];
  const float* lin2_b = (const float*)d_in[30];

  const size_t NNF = (size_t)NN * 128;        // 6.4M
  float* wsf = (float*)d_ws;
  __bf16* yh = (__bf16*)wsf;                   // y hi-plane, 6.4M bf16
  __bf16* yl = yh + NNF;                       // y lo-plane, 6.4M bf16
  __bf16* Xb = (__bf16*)(wsf + NNF);           // bf16 plane region (after y)
  __bf16* gh = Xb;                             // gather split out, 6.4M bf16
  __bf16* gl = Xb + (size_t)6400000;
  __bf16* hh[3], *hl[3];
  for (int c = 0; c < 3; ++c) {
    hh[c] = Xb + (size_t)12800000 + (size_t)c * 12800000;
    hl[c] = hh[c] + (size_t)6400000;
  }
  float* misc = wsf + NNF + (size_t)25600000;  // after plane region (51.2M bf16)
  float* pooled = misc;                        // 256*384
  float* z      = pooled + (size_t)NG * 384;
  float* scale  = z + (size_t)NG * 384;        // 384 (3 layers x 128)
  float* shift  = scale + 384;
  __bf16* whbuf = (__bf16*)(shift + 384);      // WTOTAL bf16 per plane
  __bf16* wlbuf = whbuf + (size_t)WTOTAL;
  int* rowptr   = (int*)(wlbuf + (size_t)WTOTAL);   // NN+1
  int* cursor   = rowptr + NN + 1;
  int* csr_src  = cursor + NN;
  int* bsum     = csr_src + NE;
  int* boff     = bsum + 32;

  // ---- build CSR (by dst) once ----
  hipMemsetAsync(rowptr, 0, (NN + 1) * sizeof(int), stream);
  deg_count<<<(NE + 255) / 256, 256, 0, stream>>>(dstv, rowptr, NE);
  scan_sums<<<SCAN_NB, 256, 0, stream>>>(rowptr, bsum);
  scan_offs<<<1, 64, 0, stream>>>(bsum, boff, rowptr);
  scan_final<<<SCAN_NB, 256, 0, stream>>>(boff, rowptr, cursor);
  scatter_csr<<<(NE + 255) / 256, 256, 0, stream>>>(srcv, dstv, cursor, csr_src, NE);

  // ---- pre-fold all weights + BN params (ONE launch) ----
  wprep_all<<<(WTOTAL + 255) / 256 + 1, 256, 0, stream>>>(
      cw1[0], cw1[1], cw1[2], cw2[0], cw2[1], cw2[2], whbuf, wlbuf,
      cb1[0], cg[0], cbb[0], cm[0], cv[0],
      cb1[1], cg[1], cbb[1], cm[1], cv[1],
      cb1[2], cg[2], cbb[2], cm[2], cv[2], scale, shift);

  const int w1off[3] = {WOFF_C1W1, WOFF_C2W1, WOFF_C3W1};
  const int w2off[3] = {WOFF_W2_1, WOFF_W2_2, WOFF_W2_3};
  const int ws_grid  = (NN + 127) / 128;       // 391
  const int bsp_grid = (NN + 63) / 64;         // 782
  for (int c = 0; c < 3; ++c) {
    const __bf16* w1h = whbuf + w1off[c];
    const __bf16* w1l = wlbuf + w1off[c];
    const __bf16* w2h = whbuf + w2off[c];
    const __bf16* w2l = wlbuf + w2off[c];
    if (c == 0)
      gemm_ws<false, false, true, true><<<ws_grid, 256, 0, stream>>>(
          x, nullptr, nullptr, w1h, w1l, nullptr, nullptr, yh, yl, NN, 513, 576);
    else
      gemm_bsp<false, false, true, false><<<bsp_grid, 512, 0, stream>>>(
          nullptr, hh[c - 1], hl[c - 1], w1h, w1l, nullptr, nullptr, yh, yl, NN, 128, 128);
    gather_bn_split<<<(NN + 7) / 8, 256, 0, stream>>>(
        yh, yl, rowptr, csr_src, scale + (size_t)c * 128, shift + (size_t)c * 128, gh, gl);
    gemm_bsp<true, true, true, false><<<bsp_grid, 512, 0, stream>>>(
        nullptr, gh, gl, w2h, w2l, cb2[c], nullptr, hh[c], hl[c], NN, 128, 128);
  }
  pool_mean_split<<<dim3(NG, 3), 128, 0, stream>>>(hh[0], hl[0], hh[1], hl[1], hh[2], hl[2],
                                                   batch, pooled);
  lin1_k<<<NG, 384, 0, stream>>>(pooled, lin1_w, lin1_b, z);
  lin2_k<<<4, 192, 0, stream>>>(z, lin2_w, lin2_b, (float*)d_out);
}

// Round 17
// 320.258 us; speedup vs baseline: 1.1135x; 1.0261x over previous
//
#include <hip/hip_runtime.h>

#define NN 50000
#define NE 400000
#define NG 256
#define BN_EPS 1e-5f
#define SCAN_E 8
#define SCAN_CHUNK 2048           // 256 threads * 8
#define SCAN_NB 25                // ceil(50000/2048)

// packed weight-split region offsets (per plane, bf16 elements)
#define WOFF_C1W1 0               // 128*576
#define WOFF_C2W1 73728           // 128*128
#define WOFF_C3W1 90112
#define WOFF_W2_1 106496
#define WOFF_W2_2 122880
#define WOFF_W2_3 139264
#define WTOTAL    155648

typedef __attribute__((ext_vector_type(4))) float f32x4;
typedef __bf16 bf16x8 __attribute__((ext_vector_type(8)));
typedef __bf16 bf16x4 __attribute__((ext_vector_type(4)));

__device__ __forceinline__ void mfma_bf16(f32x4& d, bf16x8 a, bf16x8 b) {
  asm volatile("v_mfma_f32_16x16x32_bf16 %0, %1, %2, %0" : "+v"(d) : "v"(a), "v"(b));
}

// ---- all-W pre-split + BN fold in ONE launch ------------------------------
__global__ __launch_bounds__(256)
void wprep_all(const float* __restrict__ w10, const float* __restrict__ w11,
               const float* __restrict__ w12, const float* __restrict__ w20,
               const float* __restrict__ w21, const float* __restrict__ w22,
               __bf16* __restrict__ wh, __bf16* __restrict__ wl,
               const float* __restrict__ b10, const float* __restrict__ g0,
               const float* __restrict__ bb0, const float* __restrict__ m0,
               const float* __restrict__ v0,
               const float* __restrict__ b11, const float* __restrict__ g1,
               const float* __restrict__ bb1, const float* __restrict__ m1,
               const float* __restrict__ v1,
               const float* __restrict__ b12, const float* __restrict__ g2,
               const float* __restrict__ bb2, const float* __restrict__ m2,
               const float* __restrict__ v2,
               float* __restrict__ scale, float* __restrict__ shift) {
  if (blockIdx.x == gridDim.x - 1) {
    for (int t = threadIdx.x; t < 384; t += 256) {
      int layer = t >> 7, c = t & 127;
      const float* b1 = layer == 0 ? b10 : layer == 1 ? b11 : b12;
      const float* g  = layer == 0 ? g0  : layer == 1 ? g1  : g2;
      const float* bb = layer == 0 ? bb0 : layer == 1 ? bb1 : bb2;
      const float* m  = layer == 0 ? m0  : layer == 1 ? m1  : m2;
      const float* v  = layer == 0 ? v0  : layer == 1 ? v1  : v2;
      float s = g[c] * rsqrtf(v[c] + BN_EPS);
      scale[t] = s;
      shift[t] = (b1[c] - m[c]) * s + bb[c];
    }
    return;
  }
  int idx = blockIdx.x * 256 + threadIdx.x;
  if (idx >= WTOTAL) return;
  const float* W; int K, Kpad, base;
  if (idx < WOFF_C2W1)      { W = w10; K = 513; Kpad = 576; base = WOFF_C1W1; }
  else if (idx < WOFF_C3W1) { W = w11; K = 128; Kpad = 128; base = WOFF_C2W1; }
  else if (idx < WOFF_W2_1) { W = w12; K = 128; Kpad = 128; base = WOFF_C3W1; }
  else if (idx < WOFF_W2_2) { W = w20; K = 128; Kpad = 128; base = WOFF_W2_1; }
  else if (idx < WOFF_W2_3) { W = w21; K = 128; Kpad = 128; base = WOFF_W2_2; }
  else                      { W = w22; K = 128; Kpad = 128; base = WOFF_W2_3; }
  int local = idx - base;
  int n = local & 127, k = local >> 7;
  float v = (k < K) ? W[(long)k * 128 + n] : 0.f;
  __bf16 h = (__bf16)v;
  wh[base + (long)n * Kpad + k] = h;
  wl[base + (long)n * Kpad + k] = (__bf16)(v - (float)h);
}

// ---- conv1 streaming GEMM — VERBATIM R16 (memcpy-vectorized A loads) ------
template<bool BIAS, bool RELU, bool OUT_SPLIT, bool A_FP32>
__global__ __launch_bounds__(256, 3)
void gemm_ws(const float* __restrict__ Af,
             const __bf16* __restrict__ Ah, const __bf16* __restrict__ Al,
             const __bf16* __restrict__ Wh, const __bf16* __restrict__ Wl,
             const float* __restrict__ bias, float* __restrict__ Cf,
             __bf16* __restrict__ Ch, __bf16* __restrict__ Cl,
             int M, int Kact, int Kpad) {
  __shared__ __align__(16) __bf16 bsh[128 * 64];   // [col][64k] swizzled octs
  __shared__ __align__(16) __bf16 bsl[128 * 64];
  const int t = threadIdx.x;
  const int wave = t >> 6, lane = t & 63;
  const int lr = lane & 15, kg = lane >> 4;
  const int r0 = blockIdx.x * 128 + wave * 32;

  bool okA[2];
  const float* apf[2];
  const __bf16 *aph[2], *apl[2];
#pragma unroll
  for (int mi = 0; mi < 2; ++mi) {
    int row = r0 + mi * 16 + lr;
    okA[mi] = row < M;
    long ro = okA[mi] ? (long)row : 0;
    if (A_FP32) { apf[mi] = Af + ro * Kact + kg * 8; aph[mi] = nullptr; apl[mi] = nullptr; }
    else { aph[mi] = Ah + ro * Kpad + kg * 8; apl[mi] = Al + ro * Kpad + kg * 8; apf[mi] = nullptr; }
  }

  f32x4 acc[2][8] = {};
  bf16x8 zero8;
#pragma unroll
  for (int j = 0; j < 8; ++j) zero8[j] = (__bf16)0.f;

  float f0[2][8], f1[2][8];                 // fp32 prefetch banks
  bf16x8 a0h[2], a0l[2], a1h[2], a1l[2];    // bf16 prefetch banks

#define PF(F, AH, AL, KQ)                                                     \
  if (A_FP32) {                                                               \
    if ((KQ) + 32 <= Kact) {                                                  \
      _Pragma("unroll") for (int mi = 0; mi < 2; ++mi) {                      \
        float tmp8[8];                                                        \
        __builtin_memcpy(&tmp8[0], apf[mi] + (KQ), 32);                       \
        _Pragma("unroll") for (int j = 0; j < 8; ++j)                         \
          F[mi][j] = okA[mi] ? tmp8[j] : 0.f;                                 \
      }                                                                       \
    } else {                                                                  \
      _Pragma("unroll") for (int mi = 0; mi < 2; ++mi)                        \
      _Pragma("unroll") for (int j = 0; j < 8; ++j) {                         \
        int k = (KQ) + kg * 8 + j;                                            \
        F[mi][j] = (okA[mi] && k < Kact) ? apf[mi][(KQ) + j] : 0.f;           \
      }                                                                       \
    }                                                                         \
  } else {                                                                    \
    _Pragma("unroll") for (int mi = 0; mi < 2; ++mi) {                        \
      AH[mi] = okA[mi] ? *(const bf16x8*)(aph[mi] + (KQ)) : zero8;            \
      AL[mi] = okA[mi] ? *(const bf16x8*)(apl[mi] + (KQ)) : zero8;            \
    }                                                                         \
  }

#define STEP(F, AH, AL, S)                                                    \
  {                                                                           \
    bf16x8 fah[2], fal[2];                                                    \
    if (A_FP32) {                                                             \
      _Pragma("unroll") for (int mi = 0; mi < 2; ++mi)                        \
      _Pragma("unroll") for (int j = 0; j < 8; ++j) {                         \
        __bf16 h = (__bf16)F[mi][j];                                          \
        fah[mi][j] = h; fal[mi][j] = (__bf16)(F[mi][j] - (float)h);           \
      }                                                                       \
    } else {                                                                  \
      _Pragma("unroll") for (int mi = 0; mi < 2; ++mi) {                      \
        fah[mi] = AH[mi]; fal[mi] = AL[mi];                                   \
      }                                                                       \
    }                                                                         \
    _Pragma("unroll") for (int ni = 0; ni < 8; ++ni) {                        \
      int col = ni * 16 + lr;                                                 \
      int po = ((S) * 4 + kg) ^ (lr & 7);                                     \
      bf16x8 fbh = *(const bf16x8*)&bsh[col * 64 + po * 8];                   \
      bf16x8 fbl = *(const bf16x8*)&bsl[col * 64 + po * 8];                   \
      _Pragma("unroll") for (int mi = 0; mi < 2; ++mi)                        \
        mfma_bf16(acc[mi][ni], fah[mi], fbh);                                 \
      _Pragma("unroll") for (int mi = 0; mi < 2; ++mi)                        \
        mfma_bf16(acc[mi][ni], fal[mi], fbh);                                 \
      _Pragma("unroll") for (int mi = 0; mi < 2; ++mi)                        \
        mfma_bf16(acc[mi][ni], fah[mi], fbl);                                 \
    }                                                                         \
  }

  PF(f0, a0h, a0l, 0);
  for (int kc0 = 0; kc0 < Kpad; kc0 += 64) {
    __syncthreads();
    // stage W chunk (both planes), XOR-swizzled oct placement
#pragma unroll
    for (int i = 0; i < 4; ++i) {
      int id = t + i * 256;
      int col = id >> 3, oct = id & 7;
      int po = oct ^ (col & 7);
      *(bf16x8*)&bsh[col * 64 + po * 8] =
          *(const bf16x8*)&Wh[(long)col * Kpad + kc0 + oct * 8];
      *(bf16x8*)&bsl[col * 64 + po * 8] =
          *(const bf16x8*)&Wl[(long)col * Kpad + kc0 + oct * 8];
    }
    __syncthreads();
    PF(f1, a1h, a1l, kc0 + 32);          // overlaps step-0 MFMAs
    STEP(f0, a0h, a0l, 0);
    if (kc0 + 64 < Kpad) { PF(f0, a0h, a0l, kc0 + 64); }  // overlaps step-1
    STEP(f1, a1h, a1l, 1);
  }
#undef PF
#undef STEP

  // epilogue: C/D layout col=lane&15, row=(lane>>4)*4+reg
#pragma unroll
  for (int mi = 0; mi < 2; ++mi) {
#pragma unroll
    for (int ni = 0; ni < 8; ++ni) {
      int col = ni * 16 + lr;
      float bv = BIAS ? bias[col] : 0.f;
#pragma unroll
      for (int r = 0; r < 4; ++r) {
        int row = r0 + mi * 16 + kg * 4 + r;
        if (row < M) {
          float v = acc[mi][ni][r] + bv;
          if (RELU) v = fmaxf(v, 0.f);
          if (OUT_SPLIT) {
            __bf16 h = (__bf16)v;
            Ch[(long)row * 128 + col] = h;
            Cl[(long)row * 128 + col] = (__bf16)(v - (float)h);
          } else {
            Cf[(long)row * 128 + col] = v;
          }
        }
      }
    }
  }
}

// ---- MFMA GEMM on pre-split bf16 — VERBATIM (proven R5/R10/R12) -----------
template<bool BIAS, bool RELU, bool OUT_SPLIT, bool A_FP32>
__global__ __launch_bounds__(512)
void gemm_bsp(const float* __restrict__ Af,
              const __bf16* __restrict__ Ah, const __bf16* __restrict__ Al,
              const __bf16* __restrict__ Wh, const __bf16* __restrict__ Wl,
              const float* __restrict__ bias, float* __restrict__ Cf,
              __bf16* __restrict__ Ch, __bf16* __restrict__ Cl,
              int M, int Kact, int Kpad) {
  __shared__ __align__(16) __bf16 ah[64 * 40];
  __shared__ __align__(16) __bf16 al[64 * 40];
  __shared__ __align__(16) __bf16 bh[128 * 40];
  __shared__ __align__(16) __bf16 bl[128 * 40];
  const int t = threadIdx.x;
  const int row0 = blockIdx.x * 64;
  const int wave = t >> 6, lane = t & 63;
  const int wr = wave >> 2, wc = wave & 3;   // 2x4 wave grid -> 32x32 tiles
  const int lr = lane & 15, kg = lane >> 4;

  // B staging: 128 rows x 4 k-octs, both planes per thread
  const int b_r = (t >> 2) & 127, b_ko = t & 3;
  const __bf16* bh_src = Wh + (long)b_r * Kpad + b_ko * 8;
  const __bf16* bl_src = Wl + (long)b_r * Kpad + b_ko * 8;
  __bf16* bh_dst = bh + b_r * 40 + b_ko * 8;
  __bf16* bl_dst = bl + b_r * 40 + b_ko * 8;

  f32x4 acc[2][2] = {};
  bf16x8 zero8;
#pragma unroll
  for (int j = 0; j < 8; ++j) zero8[j] = (__bf16)0.f;

  // plane path: 512 chunks = 2 planes x 64 rows x 4 k-octs
  const int a_pl = t >> 8, a_r8 = (t >> 2) & 63, a_ko = t & 3;
  const __bf16* a_src = (a_pl ? Al : Ah) + (long)(row0 + a_r8) * Kpad + a_ko * 8;
  __bf16* a_dst = (a_pl ? al : ah) + a_r8 * 40 + a_ko * 8;
  const bool a_ok8 = (row0 + a_r8) < M;
  // fp32 path: 64 rows x 8 k-quads(4 floats)
  const int a_rf = t >> 3, a_kq = t & 7;
  const bool a_okf = (row0 + a_rf) < M;
  const float* af_src = Af + (long)(row0 + a_rf) * Kact + a_kq * 4;
  __bf16* ahf_dst = ah + a_rf * 40 + a_kq * 4;
  __bf16* alf_dst = al + a_rf * 40 + a_kq * 4;

  bf16x8 av;
  float fa[4];
  if (A_FP32) {
#pragma unroll
    for (int j = 0; j < 4; ++j) {
      int k = a_kq * 4 + j;
      fa[j] = (a_okf && k < Kact) ? af_src[j] : 0.f;
    }
  } else {
    av = a_ok8 ? *(const bf16x8*)a_src : zero8;
  }
  bf16x8 bv0 = *(const bf16x8*)bh_src;
  bf16x8 bv1 = *(const bf16x8*)bl_src;

  for (int k0 = 0; k0 < Kpad; k0 += 32) {
    __syncthreads();
    if (A_FP32) {
      bf16x4 hv, lv;
#pragma unroll
      for (int j = 0; j < 4; ++j) {
        __bf16 h = (__bf16)fa[j];
        hv[j] = h; lv[j] = (__bf16)(fa[j] - (float)h);
      }
      *(bf16x4*)ahf_dst = hv;
      *(bf16x4*)alf_dst = lv;
    } else {
      *(bf16x8*)a_dst = av;
    }
    *(bf16x8*)bh_dst = bv0;
    *(bf16x8*)bl_dst = bv1;
    __syncthreads();
    int k1 = k0 + 32;
    if (k1 < Kpad) {            // prefetch next tile; overlaps MFMA below
      if (A_FP32) {
#pragma unroll
        for (int j = 0; j < 4; ++j) {
          int k = k1 + a_kq * 4 + j;
          fa[j] = (a_okf && k < Kact) ? af_src[k1 + j] : 0.f;
        }
      } else {
        av = a_ok8 ? *(const bf16x8*)(a_src + k1) : zero8;
      }
      bv0 = *(const bf16x8*)(bh_src + k1);
      bv1 = *(const bf16x8*)(bl_src + k1);
    }
    bf16x8 fah[2], fal[2], fbh[2], fbl[2];
#pragma unroll
    for (int mi = 0; mi < 2; ++mi) {
      int r = wr * 32 + mi * 16 + lr;
      fah[mi] = *(const bf16x8*)&ah[r * 40 + kg * 8];
      fal[mi] = *(const bf16x8*)&al[r * 40 + kg * 8];
    }
#pragma unroll
    for (int ni = 0; ni < 2; ++ni) {
      int c = wc * 32 + ni * 16 + lr;
      fbh[ni] = *(const bf16x8*)&bh[c * 40 + kg * 8];
      fbl[ni] = *(const bf16x8*)&bl[c * 40 + kg * 8];
    }
#pragma unroll
    for (int mi = 0; mi < 2; ++mi)
#pragma unroll
      for (int ni = 0; ni < 2; ++ni) {
        mfma_bf16(acc[mi][ni], fah[mi], fbh[ni]);
        mfma_bf16(acc[mi][ni], fal[mi], fbh[ni]);
        mfma_bf16(acc[mi][ni], fah[mi], fbl[ni]);
      }
  }
  // epilogue: C/D layout col=lane&15, row=(lane>>4)*4+reg
#pragma unroll
  for (int mi = 0; mi < 2; ++mi) {
#pragma unroll
    for (int ni = 0; ni < 2; ++ni) {
      int col = wc * 32 + ni * 16 + lr;
      float bv = BIAS ? bias[col] : 0.f;
#pragma unroll
      for (int r = 0; r < 4; ++r) {
        int row = row0 + wr * 32 + mi * 16 + kg * 4 + r;
        if (row < M) {
          float v = acc[mi][ni][r] + bv;
          if (RELU) v = fmaxf(v, 0.f);
          if (OUT_SPLIT) {
            __bf16 h = (__bf16)v;
            Ch[(long)row * 128 + col] = h;
            Cl[(long)row * 128 + col] = (__bf16)(v - (float)h);
          } else {
            Cf[(long)row * 128 + col] = v;
          }
        }
      }
    }
  }
}

// ---------------- CSR build -------------------------------------------------
__global__ __launch_bounds__(256)
void deg_count(const int* __restrict__ dst, int* __restrict__ deg, int E) {
  int e = blockIdx.x * 256 + threadIdx.x;
  if (e < E) atomicAdd(&deg[dst[e]], 1);
}

__global__ __launch_bounds__(256)
void scan_sums(const int* __restrict__ deg, int* __restrict__ bsum) {
  __shared__ int sm[256];
  int base = blockIdx.x * SCAN_CHUNK + threadIdx.x * SCAN_E;
  int s = 0;
#pragma unroll
  for (int k = 0; k < SCAN_E; ++k) { int i = base + k; if (i < NN) s += deg[i]; }
  sm[threadIdx.x] = s; __syncthreads();
  for (int off = 128; off > 0; off >>= 1) {
    if (threadIdx.x < off) sm[threadIdx.x] += sm[threadIdx.x + off];
    __syncthreads();
  }
  if (threadIdx.x == 0) bsum[blockIdx.x] = sm[0];
}

__global__ void scan_offs(const int* __restrict__ bsum, int* __restrict__ boff,
                          int* __restrict__ rowptr) {
  if (threadIdx.x == 0) {
    int run = 0;
    for (int i = 0; i < SCAN_NB; ++i) { boff[i] = run; run += bsum[i]; }
    rowptr[NN] = run;
  }
}

__global__ __launch_bounds__(256)
void scan_final(const int* __restrict__ boff, int* __restrict__ rowptr,
                int* __restrict__ cursor) {
  __shared__ int sm[256];
  int t = threadIdx.x;
  int base = blockIdx.x * SCAN_CHUNK + t * SCAN_E;
  int v[SCAN_E]; int s = 0;
#pragma unroll
  for (int k = 0; k < SCAN_E; ++k) { int i = base + k; v[k] = (i < NN) ? rowptr[i] : 0; s += v[k]; }
  sm[t] = s; __syncthreads();
  for (int off = 1; off < 256; off <<= 1) {
    int val = sm[t]; int add = (t >= off) ? sm[t - off] : 0;
    __syncthreads();
    sm[t] = val + add;
    __syncthreads();
  }
  int excl = (t == 0 ? 0 : sm[t - 1]) + boff[blockIdx.x];
#pragma unroll
  for (int k = 0; k < SCAN_E; ++k) {
    int i = base + k;
    if (i < NN) { rowptr[i] = excl; cursor[i] = excl; }
    excl += v[k];
  }
}

__global__ __launch_bounds__(256)
void scatter_csr(const int* __restrict__ src, const int* __restrict__ dst,
                 int* __restrict__ cursor, int* __restrict__ csr_src, int E) {
  int e = blockIdx.x * 256 + threadIdx.x;
  if (e < E) {
    int d = dst[e];
    int pos = atomicAdd(&cursor[d], 1);
    csr_src[pos] = src[e];
  }
}

// ------- gather+sum over in-edges, fused BN+ReLU ---------------------------
// 16 lanes per node (bf16x8 = 16B per lane), 4 nodes per wave: one wave-load
// instruction covers 4 edges (1 KB) -> ~2x fewer VMEM instructions vs R16.
__global__ __launch_bounds__(256)
void gather_bn_split(const __bf16* __restrict__ yh, const __bf16* __restrict__ yl,
                     const int* __restrict__ rowptr,
                     const int* __restrict__ csr_src, const float* __restrict__ scale,
                     const float* __restrict__ shift, __bf16* __restrict__ oh,
                     __bf16* __restrict__ ol) {
  const int grp = threadIdx.x >> 4;        // 16 node-groups per block
  const int lane = threadIdx.x & 15;       // 16 lanes x 8 bf16 = 128 feats
  const int node = blockIdx.x * 16 + grp;
  if (node >= NN) return;
  int s = rowptr[node], e = rowptr[node + 1];
  // self term: hi + lo (fp32-exact reconstruction)
  bf16x8 sh8 = *(const bf16x8*)&yh[(long)node * 128 + lane * 8];
  bf16x8 sl8 = *(const bf16x8*)&yl[(long)node * 128 + lane * 8];
  float a[8], b[8];
#pragma unroll
  for (int j = 0; j < 8; ++j) { a[j] = (float)sh8[j] + (float)sl8[j]; b[j] = 0.f; }
  int i = s;
  for (; i + 3 < e; i += 4) {
    int s0 = csr_src[i], s1 = csr_src[i + 1], s2 = csr_src[i + 2], s3 = csr_src[i + 3];
    bf16x8 v0 = *(const bf16x8*)&yh[(long)s0 * 128 + lane * 8];
    bf16x8 v1 = *(const bf16x8*)&yh[(long)s1 * 128 + lane * 8];
    bf16x8 v2 = *(const bf16x8*)&yh[(long)s2 * 128 + lane * 8];
    bf16x8 v3 = *(const bf16x8*)&yh[(long)s3 * 128 + lane * 8];
#pragma unroll
    for (int j = 0; j < 8; ++j) {
      a[j] += (float)v0[j]; b[j] += (float)v1[j];
      a[j] += (float)v2[j]; b[j] += (float)v3[j];
    }
  }
  for (; i < e; ++i) {
    int sn = csr_src[i];
    bf16x8 v = *(const bf16x8*)&yh[(long)sn * 128 + lane * 8];
#pragma unroll
    for (int j = 0; j < 8; ++j) a[j] += (float)v[j];
  }
  f32x4 sc0 = ((const f32x4*)scale)[lane * 2];
  f32x4 sc1 = ((const f32x4*)scale)[lane * 2 + 1];
  f32x4 sh0 = ((const f32x4*)shift)[lane * 2];
  f32x4 sh1 = ((const f32x4*)shift)[lane * 2 + 1];
  float sc[8] = {sc0.x, sc0.y, sc0.z, sc0.w, sc1.x, sc1.y, sc1.z, sc1.w};
  float sf[8] = {sh0.x, sh0.y, sh0.z, sh0.w, sh1.x, sh1.y, sh1.z, sh1.w};
  bf16x8 hv, lv;
#pragma unroll
  for (int j = 0; j < 8; ++j) {
    float o = fmaxf((a[j] + b[j]) * sc[j] + sf[j], 0.f);
    __bf16 h = (__bf16)o;
    hv[j] = h;
    lv[j] = (__bf16)(o - (float)h);
  }
  *(bf16x8*)&oh[(long)node * 128 + lane * 8] = hv;
  *(bf16x8*)&ol[(long)node * 128 + lane * 8] = lv;
}

// ---- pool with fused graph-bounds; hi-plane only --------------------------
__global__ __launch_bounds__(128)
void pool_mean_split(const __bf16* __restrict__ h0h, const __bf16* __restrict__ h0l,
                     const __bf16* __restrict__ h1h, const __bf16* __restrict__ h1l,
                     const __bf16* __restrict__ h2h, const __bf16* __restrict__ h2l,
                     const int* __restrict__ batch, float* __restrict__ pooled) {
  __shared__ int se[2];
  int layer = blockIdx.y;
  const __bf16* hh = (layer == 0) ? h0h : (layer == 1) ? h1h : h2h;
  int g = blockIdx.x, c = threadIdx.x;
  if (threadIdx.x < 2) {
    int target = g + (int)threadIdx.x;   // lower bound of batch >= target
    int lo = 0, hi = NN;
    while (lo < hi) {
      int mid = (lo + hi) >> 1;
      if (batch[mid] < target) lo = mid + 1; else hi = mid;
    }
    se[threadIdx.x] = lo;
  }
  __syncthreads();
  int s = se[0], e = se[1];
  float a0 = 0.f, a1 = 0.f, a2 = 0.f, a3 = 0.f;
  int i = s;
  for (; i + 3 < e; i += 4) {
    a0 += (float)hh[(long)i * 128 + c];
    a1 += (float)hh[(long)(i + 1) * 128 + c];
    a2 += (float)hh[(long)(i + 2) * 128 + c];
    a3 += (float)hh[(long)(i + 3) * 128 + c];
  }
  for (; i < e; ++i)
    a0 += (float)hh[(long)i * 128 + c];
  float acc = (a0 + a1) + (a2 + a3);
  pooled[g * 384 + layer * 128 + c] = acc / fmaxf((float)(e - s), 1.f);
}

__global__ __launch_bounds__(384)
void lin1_k(const float* __restrict__ pooled, const float* __restrict__ w,
            const float* __restrict__ b, float* __restrict__ z) {
  __shared__ float pr[384];
  int mrow = blockIdx.x, t = threadIdx.x;
  pr[t] = pooled[mrow * 384 + t];
  __syncthreads();
  float acc = b[t];
  for (int k = 0; k < 384; ++k) acc += pr[k] * w[k * 384 + t];
  z[mrow * 384 + t] = fmaxf(acc, 0.f);
}

__global__ __launch_bounds__(192)
void lin2_k(const float* __restrict__ z, const float* __restrict__ w,
            const float* __restrict__ b, float* __restrict__ out) {
  int idx = blockIdx.x * 192 + threadIdx.x;
  if (idx >= NG * 3) return;
  int mrow = idx / 3, j = idx % 3;
  float acc = b[j];
  for (int k = 0; k < 384; ++k) acc += z[mrow * 384 + k] * w[k * 3 + j];
  out[idx] = acc;
}

extern "C" void kernel_launch(void* const* d_in, const int* in_sizes, int n_in,
                              void* d_out, int out_size, void* d_ws, size_t ws_size,
                              hipStream_t stream) {
  const float* x = (const float*)d_in[0];
  const int* ei = (const int*)d_in[1];
  const int* batch = (const int*)d_in[2];
  const int* srcv = ei;
  const int* dstv = ei + NE;
  const float* cw1[3] = {(const float*)d_in[3], (const float*)d_in[11], (const float*)d_in[19]};
  const float* cb1[3] = {(const float*)d_in[4], (const float*)d_in[12], (const float*)d_in[20]};
  const float* cg[3]  = {(const float*)d_in[5], (const float*)d_in[13], (const float*)d_in[21]};
  const float* cbb[3] = {(const float*)d_in[6], (const float*)d_in[14], (const float*)d_in[22]};
  const float* cm[3]  = {(const float*)d_in[7], (const float*)d_in[15], (const float*)d_in[23]};
  const float* cv[3]  = {(const float*)d_in[8], (const float*)d_in[16], (const float*)d_in[24]};
  const float* cw2[3] = {(const float*)d_in[9], (const float*)d_in[17], (const float*)d_in[25]};
  const float* cb2[3] = {(const float*)d_in[10], (const float*)d_in[18], (const float*)d_in[26]};
  const float* lin1_w = (const float*)d_in[27];
  const float* lin1_b = (const float*)d_in[28];
  const float* lin2_w = (const float*)d_in[29];
  const float* lin2_b = (const float*)d_in[30];

  const size_t NNF = (size_t)NN * 128;        // 6.4M
  float* wsf = (float*)d_ws;
  __bf16* yh = (__bf16*)wsf;                   // y hi-plane, 6.4M bf16
  __bf16* yl = yh + NNF;                       // y lo-plane, 6.4M bf16
  __bf16* Xb = (__bf16*)(wsf + NNF);           // bf16 plane region (after y)
  __bf16* gh = Xb;                             // gather split out, 6.4M bf16
  __bf16* gl = Xb + (size_t)6400000;
  __bf16* hh[3], *hl[3];
  for (int c = 0; c < 3; ++c) {
    hh[c] = Xb + (size_t)12800000 + (size_t)c * 12800000;
    hl[c] = hh[c] + (size_t)6400000;
  }
  float* misc = wsf + NNF + (size_t)25600000;  // after plane region (51.2M bf16)
  float* pooled = misc;                        // 256*384
  float* z      = pooled + (size_t)NG * 384;
  float* scale  = z + (size_t)NG * 384;        // 384 (3 layers x 128)
  float* shift  = scale + 384;
  __bf16* whbuf = (__bf16*)(shift + 384);      // WTOTAL bf16 per plane
  __bf16* wlbuf = whbuf + (size_t)WTOTAL;
  int* rowptr   = (int*)(wlbuf + (size_t)WTOTAL);   // NN+1
  int* cursor   = rowptr + NN + 1;
  int* csr_src  = cursor + NN;
  int* bsum     = csr_src + NE;
  int* boff     = bsum + 32;

  // ---- build CSR (by dst) once ----
  hipMemsetAsync(rowptr, 0, (NN + 1) * sizeof(int), stream);
  deg_count<<<(NE + 255) / 256, 256, 0, stream>>>(dstv, rowptr, NE);
  scan_sums<<<SCAN_NB, 256, 0, stream>>>(rowptr, bsum);
  scan_offs<<<1, 64, 0, stream>>>(bsum, boff, rowptr);
  scan_final<<<SCAN_NB, 256, 0, stream>>>(boff, rowptr, cursor);
  scatter_csr<<<(NE + 255) / 256, 256, 0, stream>>>(srcv, dstv, cursor, csr_src, NE);

  // ---- pre-fold all weights + BN params (ONE launch) ----
  wprep_all<<<(WTOTAL + 255) / 256 + 1, 256, 0, stream>>>(
      cw1[0], cw1[1], cw1[2], cw2[0], cw2[1], cw2[2], whbuf, wlbuf,
      cb1[0], cg[0], cbb[0], cm[0], cv[0],
      cb1[1], cg[1], cbb[1], cm[1], cv[1],
      cb1[2], cg[2], cbb[2], cm[2], cv[2], scale, shift);

  const int w1off[3] = {WOFF_C1W1, WOFF_C2W1, WOFF_C3W1};
  const int w2off[3] = {WOFF_W2_1, WOFF_W2_2, WOFF_W2_3};
  const int ws_grid  = (NN + 127) / 128;       // 391
  const int bsp_grid = (NN + 63) / 64;         // 782
  for (int c = 0; c < 3; ++c) {
    const __bf16* w1h = whbuf + w1off[c];
    const __bf16* w1l = wlbuf + w1off[c];
    const __bf16* w2h = whbuf + w2off[c];
    const __bf16* w2l = wlbuf + w2off[c];
    if (c == 0)
      gemm_ws<false, false, true, true><<<ws_grid, 256, 0, stream>>>(
          x, nullptr, nullptr, w1h, w1l, nullptr, nullptr, yh, yl, NN, 513, 576);
    else
      gemm_bsp<false, false, true, false><<<bsp_grid, 512, 0, stream>>>(
          nullptr, hh[c - 1], hl[c - 1], w1h, w1l, nullptr, nullptr, yh, yl, NN, 128, 128);
    gather_bn_split<<<(NN + 15) / 16, 256, 0, stream>>>(
        yh, yl, rowptr, csr_src, scale + (size_t)c * 128, shift + (size_t)c * 128, gh, gl);
    gemm_bsp<true, true, true, false><<<bsp_grid, 512, 0, stream>>>(
        nullptr, gh, gl, w2h, w2l, cb2[c], nullptr, hh[c], hl[c], NN, 128, 128);
  }
  pool_mean_split<<<dim3(NG, 3), 128, 0, stream>>>(hh[0], hl[0], hh[1], hl[1], hh[2], hl[2],
                                                   batch, pooled);
  lin1_k<<<NG, 384, 0, stream>>>(pooled, lin1_w, lin1_b, z);
  lin2_k<<<4, 192, 0, stream>>>(z, lin2_w, lin2_b, (float*)d_out);
}

// Round 19
// 319.935 us; speedup vs baseline: 1.1146x; 1.0010x over previous
//
#include <hip/hip_runtime.h>

#define NN 50000
#define NE 400000
#define NG 256
#define BN_EPS 1e-5f
#define SCAN_E 8
#define SCAN_CHUNK 2048           // 256 threads * 8
#define SCAN_NB 25                // ceil(50000/2048)

// packed weight-split region offsets (per plane, bf16 elements)
#define WOFF_C1W1 0               // 128*576
#define WOFF_C2W1 73728           // 128*128
#define WOFF_C3W1 90112
#define WOFF_W2_1 106496
#define WOFF_W2_2 122880
#define WOFF_W2_3 139264
#define WTOTAL    155648

typedef __attribute__((ext_vector_type(4))) float f32x4;
typedef __bf16 bf16x8 __attribute__((ext_vector_type(8)));
typedef __bf16 bf16x4 __attribute__((ext_vector_type(4)));

__device__ __forceinline__ void mfma_bf16(f32x4& d, bf16x8 a, bf16x8 b) {
  asm volatile("v_mfma_f32_16x16x32_bf16 %0, %1, %2, %0" : "+v"(d) : "v"(a), "v"(b));
}

// ---- all-W pre-split + BN fold in ONE launch ------------------------------
__global__ __launch_bounds__(256)
void wprep_all(const float* __restrict__ w10, const float* __restrict__ w11,
               const float* __restrict__ w12, const float* __restrict__ w20,
               const float* __restrict__ w21, const float* __restrict__ w22,
               __bf16* __restrict__ wh, __bf16* __restrict__ wl,
               const float* __restrict__ b10, const float* __restrict__ g0,
               const float* __restrict__ bb0, const float* __restrict__ m0,
               const float* __restrict__ v0,
               const float* __restrict__ b11, const float* __restrict__ g1,
               const float* __restrict__ bb1, const float* __restrict__ m1,
               const float* __restrict__ v1,
               const float* __restrict__ b12, const float* __restrict__ g2,
               const float* __restrict__ bb2, const float* __restrict__ m2,
               const float* __restrict__ v2,
               float* __restrict__ scale, float* __restrict__ shift) {
  if (blockIdx.x == gridDim.x - 1) {
    for (int t = threadIdx.x; t < 384; t += 256) {
      int layer = t >> 7, c = t & 127;
      const float* b1 = layer == 0 ? b10 : layer == 1 ? b11 : b12;
      const float* g  = layer == 0 ? g0  : layer == 1 ? g1  : g2;
      const float* bb = layer == 0 ? bb0 : layer == 1 ? bb1 : bb2;
      const float* m  = layer == 0 ? m0  : layer == 1 ? m1  : m2;
      const float* v  = layer == 0 ? v0  : layer == 1 ? v1  : v2;
      float s = g[c] * rsqrtf(v[c] + BN_EPS);
      scale[t] = s;
      shift[t] = (b1[c] - m[c]) * s + bb[c];
    }
    return;
  }
  int idx = blockIdx.x * 256 + threadIdx.x;
  if (idx >= WTOTAL) return;
  const float* W; int K, Kpad, base;
  if (idx < WOFF_C2W1)      { W = w10; K = 513; Kpad = 576; base = WOFF_C1W1; }
  else if (idx < WOFF_C3W1) { W = w11; K = 128; Kpad = 128; base = WOFF_C2W1; }
  else if (idx < WOFF_W2_1) { W = w12; K = 128; Kpad = 128; base = WOFF_C3W1; }
  else if (idx < WOFF_W2_2) { W = w20; K = 128; Kpad = 128; base = WOFF_W2_1; }
  else if (idx < WOFF_W2_3) { W = w21; K = 128; Kpad = 128; base = WOFF_W2_2; }
  else                      { W = w22; K = 128; Kpad = 128; base = WOFF_W2_3; }
  int local = idx - base;
  int n = local & 127, k = local >> 7;
  float v = (k < K) ? W[(long)k * 128 + n] : 0.f;
  __bf16 h = (__bf16)v;
  wh[base + (long)n * Kpad + k] = h;
  wl[base + (long)n * Kpad + k] = (__bf16)(v - (float)h);
}

// ---- conv1 streaming GEMM — VERBATIM R16/R17 (memcpy-vectorized A) --------
template<bool BIAS, bool RELU, bool OUT_SPLIT, bool A_FP32>
__global__ __launch_bounds__(256, 3)
void gemm_ws(const float* __restrict__ Af,
             const __bf16* __restrict__ Ah, const __bf16* __restrict__ Al,
             const __bf16* __restrict__ Wh, const __bf16* __restrict__ Wl,
             const float* __restrict__ bias, float* __restrict__ Cf,
             __bf16* __restrict__ Ch, __bf16* __restrict__ Cl,
             int M, int Kact, int Kpad) {
  __shared__ __align__(16) __bf16 bsh[128 * 64];   // [col][64k] swizzled octs
  __shared__ __align__(16) __bf16 bsl[128 * 64];
  const int t = threadIdx.x;
  const int wave = t >> 6, lane = t & 63;
  const int lr = lane & 15, kg = lane >> 4;
  const int r0 = blockIdx.x * 128 + wave * 32;

  bool okA[2];
  const float* apf[2];
  const __bf16 *aph[2], *apl[2];
#pragma unroll
  for (int mi = 0; mi < 2; ++mi) {
    int row = r0 + mi * 16 + lr;
    okA[mi] = row < M;
    long ro = okA[mi] ? (long)row : 0;
    if (A_FP32) { apf[mi] = Af + ro * Kact + kg * 8; aph[mi] = nullptr; apl[mi] = nullptr; }
    else { aph[mi] = Ah + ro * Kpad + kg * 8; apl[mi] = Al + ro * Kpad + kg * 8; apf[mi] = nullptr; }
  }

  f32x4 acc[2][8] = {};
  bf16x8 zero8;
#pragma unroll
  for (int j = 0; j < 8; ++j) zero8[j] = (__bf16)0.f;

  float f0[2][8], f1[2][8];                 // fp32 prefetch banks
  bf16x8 a0h[2], a0l[2], a1h[2], a1l[2];    // bf16 prefetch banks

#define PF(F, AH, AL, KQ)                                                     \
  if (A_FP32) {                                                               \
    if ((KQ) + 32 <= Kact) {                                                  \
      _Pragma("unroll") for (int mi = 0; mi < 2; ++mi) {                      \
        float tmp8[8];                                                        \
        __builtin_memcpy(&tmp8[0], apf[mi] + (KQ), 32);                       \
        _Pragma("unroll") for (int j = 0; j < 8; ++j)                         \
          F[mi][j] = okA[mi] ? tmp8[j] : 0.f;                                 \
      }                                                                       \
    } else {                                                                  \
      _Pragma("unroll") for (int mi = 0; mi < 2; ++mi)                        \
      _Pragma("unroll") for (int j = 0; j < 8; ++j) {                         \
        int k = (KQ) + kg * 8 + j;                                            \
        F[mi][j] = (okA[mi] && k < Kact) ? apf[mi][(KQ) + j] : 0.f;           \
      }                                                                       \
    }                                                                         \
  } else {                                                                    \
    _Pragma("unroll") for (int mi = 0; mi < 2; ++mi) {                        \
      AH[mi] = okA[mi] ? *(const bf16x8*)(aph[mi] + (KQ)) : zero8;            \
      AL[mi] = okA[mi] ? *(const bf16x8*)(apl[mi] + (KQ)) : zero8;            \
    }                                                                         \
  }

#define STEP(F, AH, AL, S)                                                    \
  {                                                                           \
    bf16x8 fah[2], fal[2];                                                    \
    if (A_FP32) {                                                             \
      _Pragma("unroll") for (int mi = 0; mi < 2; ++mi)                        \
      _Pragma("unroll") for (int j = 0; j < 8; ++j) {                         \
        __bf16 h = (__bf16)F[mi][j];                                          \
        fah[mi][j] = h; fal[mi][j] = (__bf16)(F[mi][j] - (float)h);           \
      }                                                                       \
    } else {                                                                  \
      _Pragma("unroll") for (int mi = 0; mi < 2; ++mi) {                      \
        fah[mi] = AH[mi]; fal[mi] = AL[mi];                                   \
      }                                                                       \
    }                                                                         \
    _Pragma("unroll") for (int ni = 0; ni < 8; ++ni) {                        \
      int col = ni * 16 + lr;                                                 \
      int po = ((S) * 4 + kg) ^ (lr & 7);                                     \
      bf16x8 fbh = *(const bf16x8*)&bsh[col * 64 + po * 8];                   \
      bf16x8 fbl = *(const bf16x8*)&bsl[col * 64 + po * 8];                   \
      _Pragma("unroll") for (int mi = 0; mi < 2; ++mi)                        \
        mfma_bf16(acc[mi][ni], fah[mi], fbh);                                 \
      _Pragma("unroll") for (int mi = 0; mi < 2; ++mi)                        \
        mfma_bf16(acc[mi][ni], fal[mi], fbh);                                 \
      _Pragma("unroll") for (int mi = 0; mi < 2; ++mi)                        \
        mfma_bf16(acc[mi][ni], fah[mi], fbl);                                 \
    }                                                                         \
  }

  PF(f0, a0h, a0l, 0);
  for (int kc0 = 0; kc0 < Kpad; kc0 += 64) {
    __syncthreads();
    // stage W chunk (both planes), XOR-swizzled oct placement
#pragma unroll
    for (int i = 0; i < 4; ++i) {
      int id = t + i * 256;
      int col = id >> 3, oct = id & 7;
      int po = oct ^ (col & 7);
      *(bf16x8*)&bsh[col * 64 + po * 8] =
          *(const bf16x8*)&Wh[(long)col * Kpad + kc0 + oct * 8];
      *(bf16x8*)&bsl[col * 64 + po * 8] =
          *(const bf16x8*)&Wl[(long)col * Kpad + kc0 + oct * 8];
    }
    __syncthreads();
    PF(f1, a1h, a1l, kc0 + 32);          // overlaps step-0 MFMAs
    STEP(f0, a0h, a0l, 0);
    if (kc0 + 64 < Kpad) { PF(f0, a0h, a0l, kc0 + 64); }  // overlaps step-1
    STEP(f1, a1h, a1l, 1);
  }
#undef PF
#undef STEP

  // epilogue: C/D layout col=lane&15, row=(lane>>4)*4+reg
#pragma unroll
  for (int mi = 0; mi < 2; ++mi) {
#pragma unroll
    for (int ni = 0; ni < 8; ++ni) {
      int col = ni * 16 + lr;
      float bv = BIAS ? bias[col] : 0.f;
#pragma unroll
      for (int r = 0; r < 4; ++r) {
        int row = r0 + mi * 16 + kg * 4 + r;
        if (row < M) {
          float v = acc[mi][ni][r] + bv;
          if (RELU) v = fmaxf(v, 0.f);
          if (OUT_SPLIT) {
            __bf16 h = (__bf16)v;
            Ch[(long)row * 128 + col] = h;
            Cl[(long)row * 128 + col] = (__bf16)(v - (float)h);
          } else {
            Cf[(long)row * 128 + col] = v;
          }
        }
      }
    }
  }
}

// ---- MFMA GEMM on pre-split bf16 — VERBATIM (proven R5/R10/R12) -----------
template<bool BIAS, bool RELU, bool OUT_SPLIT, bool A_FP32>
__global__ __launch_bounds__(512)
void gemm_bsp(const float* __restrict__ Af,
              const __bf16* __restrict__ Ah, const __bf16* __restrict__ Al,
              const __bf16* __restrict__ Wh, const __bf16* __restrict__ Wl,
              const float* __restrict__ bias, float* __restrict__ Cf,
              __bf16* __restrict__ Ch, __bf16* __restrict__ Cl,
              int M, int Kact, int Kpad) {
  __shared__ __align__(16) __bf16 ah[64 * 40];
  __shared__ __align__(16) __bf16 al[64 * 40];
  __shared__ __align__(16) __bf16 bh[128 * 40];
  __shared__ __align__(16) __bf16 bl[128 * 40];
  const int t = threadIdx.x;
  const int row0 = blockIdx.x * 64;
  const int wave = t >> 6, lane = t & 63;
  const int wr = wave >> 2, wc = wave & 3;   // 2x4 wave grid -> 32x32 tiles
  const int lr = lane & 15, kg = lane >> 4;

  const int b_r = (t >> 2) & 127, b_ko = t & 3;
  const __bf16* bh_src = Wh + (long)b_r * Kpad + b_ko * 8;
  const __bf16* bl_src = Wl + (long)b_r * Kpad + b_ko * 8;
  __bf16* bh_dst = bh + b_r * 40 + b_ko * 8;
  __bf16* bl_dst = bl + b_r * 40 + b_ko * 8;

  f32x4 acc[2][2] = {};
  bf16x8 zero8;
#pragma unroll
  for (int j = 0; j < 8; ++j) zero8[j] = (__bf16)0.f;

  const int a_pl = t >> 8, a_r8 = (t >> 2) & 63, a_ko = t & 3;
  const __bf16* a_src = (a_pl ? Al : Ah) + (long)(row0 + a_r8) * Kpad + a_ko * 8;
  __bf16* a_dst = (a_pl ? al : ah) + a_r8 * 40 + a_ko * 8;
  const bool a_ok8 = (row0 + a_r8) < M;
  const int a_rf = t >> 3, a_kq = t & 7;
  const bool a_okf = (row0 + a_rf) < M;
  const float* af_src = Af + (long)(row0 + a_rf) * Kact + a_kq * 4;
  __bf16* ahf_dst = ah + a_rf * 40 + a_kq * 4;
  __bf16* alf_dst = al + a_rf * 40 + a_kq * 4;

  bf16x8 av;
  float fa[4];
  if (A_FP32) {
#pragma unroll
    for (int j = 0; j < 4; ++j) {
      int k = a_kq * 4 + j;
      fa[j] = (a_okf && k < Kact) ? af_src[j] : 0.f;
    }
  } else {
    av = a_ok8 ? *(const bf16x8*)a_src : zero8;
  }
  bf16x8 bv0 = *(const bf16x8*)bh_src;
  bf16x8 bv1 = *(const bf16x8*)bl_src;

  for (int k0 = 0; k0 < Kpad; k0 += 32) {
    __syncthreads();
    if (A_FP32) {
      bf16x4 hv, lv;
#pragma unroll
      for (int j = 0; j < 4; ++j) {
        __bf16 h = (__bf16)fa[j];
        hv[j] = h; lv[j] = (__bf16)(fa[j] - (float)h);
      }
      *(bf16x4*)ahf_dst = hv;
      *(bf16x4*)alf_dst = lv;
    } else {
      *(bf16x8*)a_dst = av;
    }
    *(bf16x8*)bh_dst = bv0;
    *(bf16x8*)bl_dst = bv1;
    __syncthreads();
    int k1 = k0 + 32;
    if (k1 < Kpad) {            // prefetch next tile; overlaps MFMA below
      if (A_FP32) {
#pragma unroll
        for (int j = 0; j < 4; ++j) {
          int k = k1 + a_kq * 4 + j;
          fa[j] = (a_okf && k < Kact) ? af_src[k1 + j] : 0.f;
        }
      } else {
        av = a_ok8 ? *(const bf16x8*)(a_src + k1) : zero8;
      }
      bv0 = *(const bf16x8*)(bh_src + k1);
      bv1 = *(const bf16x8*)(bl_src + k1);
    }
    bf16x8 fah[2], fal[2], fbh[2], fbl[2];
#pragma unroll
    for (int mi = 0; mi < 2; ++mi) {
      int r = wr * 32 + mi * 16 + lr;
      fah[mi] = *(const bf16x8*)&ah[r * 40 + kg * 8];
      fal[mi] = *(const bf16x8*)&al[r * 40 + kg * 8];
    }
#pragma unroll
    for (int ni = 0; ni < 2; ++ni) {
      int c = wc * 32 + ni * 16 + lr;
      fbh[ni] = *(const bf16x8*)&bh[c * 40 + kg * 8];
      fbl[ni] = *(const bf16x8*)&bl[c * 40 + kg * 8];
    }
#pragma unroll
    for (int mi = 0; mi < 2; ++mi)
#pragma unroll
      for (int ni = 0; ni < 2; ++ni) {
        mfma_bf16(acc[mi][ni], fah[mi], fbh[ni]);
        mfma_bf16(acc[mi][ni], fal[mi], fbh[ni]);
        mfma_bf16(acc[mi][ni], fah[mi], fbl[ni]);
      }
  }
  // epilogue: C/D layout col=lane&15, row=(lane>>4)*4+reg
#pragma unroll
  for (int mi = 0; mi < 2; ++mi) {
#pragma unroll
    for (int ni = 0; ni < 2; ++ni) {
      int col = wc * 32 + ni * 16 + lr;
      float bv = BIAS ? bias[col] : 0.f;
#pragma unroll
      for (int r = 0; r < 4; ++r) {
        int row = row0 + wr * 32 + mi * 16 + kg * 4 + r;
        if (row < M) {
          float v = acc[mi][ni][r] + bv;
          if (RELU) v = fmaxf(v, 0.f);
          if (OUT_SPLIT) {
            __bf16 h = (__bf16)v;
            Ch[(long)row * 128 + col] = h;
            Cl[(long)row * 128 + col] = (__bf16)(v - (float)h);
          } else {
            Cf[(long)row * 128 + col] = v;
          }
        }
      }
    }
  }
}

// ---------------- CSR build -------------------------------------------------
__global__ __launch_bounds__(256)
void deg_count(const int* __restrict__ dst, int* __restrict__ deg, int E) {
  int e = blockIdx.x * 256 + threadIdx.x;
  if (e < E) atomicAdd(&deg[dst[e]], 1);
}

__global__ __launch_bounds__(256)
void scan_sums(const int* __restrict__ deg, int* __restrict__ bsum) {
  __shared__ int sm[256];
  int base = blockIdx.x * SCAN_CHUNK + threadIdx.x * SCAN_E;
  int s = 0;
#pragma unroll
  for (int k = 0; k < SCAN_E; ++k) { int i = base + k; if (i < NN) s += deg[i]; }
  sm[threadIdx.x] = s; __syncthreads();
  for (int off = 128; off > 0; off >>= 1) {
    if (threadIdx.x < off) sm[threadIdx.x] += sm[threadIdx.x + off];
    __syncthreads();
  }
  if (threadIdx.x == 0) bsum[blockIdx.x] = sm[0];
}

__global__ void scan_offs(const int* __restrict__ bsum, int* __restrict__ boff,
                          int* __restrict__ rowptr) {
  if (threadIdx.x == 0) {
    int run = 0;
    for (int i = 0; i < SCAN_NB; ++i) { boff[i] = run; run += bsum[i]; }
    rowptr[NN] = run;
  }
}

__global__ __launch_bounds__(256)
void scan_final(const int* __restrict__ boff, int* __restrict__ rowptr,
                int* __restrict__ cursor) {
  __shared__ int sm[256];
  int t = threadIdx.x;
  int base = blockIdx.x * SCAN_CHUNK + t * SCAN_E;
  int v[SCAN_E]; int s = 0;
#pragma unroll
  for (int k = 0; k < SCAN_E; ++k) { int i = base + k; v[k] = (i < NN) ? rowptr[i] : 0; s += v[k]; }
  sm[t] = s; __syncthreads();
  for (int off = 1; off < 256; off <<= 1) {
    int val = sm[t]; int add = (t >= off) ? sm[t - off] : 0;
    __syncthreads();
    sm[t] = val + add;
    __syncthreads();
  }
  int excl = (t == 0 ? 0 : sm[t - 1]) + boff[blockIdx.x];
#pragma unroll
  for (int k = 0; k < SCAN_E; ++k) {
    int i = base + k;
    if (i < NN) { rowptr[i] = excl; cursor[i] = excl; }
    excl += v[k];
  }
}

__global__ __launch_bounds__(256)
void scatter_csr(const int* __restrict__ src, const int* __restrict__ dst,
                 int* __restrict__ cursor, int* __restrict__ csr_src, int E) {
  int e = blockIdx.x * 256 + threadIdx.x;
  if (e < E) {
    int d = dst[e];
    int pos = atomicAdd(&cursor[d], 1);
    csr_src[pos] = src[e];
  }
}

// ------- gather+sum over in-edges, fused BN+ReLU — VERBATIM R17 ------------
__global__ __launch_bounds__(256)
void gather_bn_split(const __bf16* __restrict__ yh, const __bf16* __restrict__ yl,
                     const int* __restrict__ rowptr,
                     const int* __restrict__ csr_src, const float* __restrict__ scale,
                     const float* __restrict__ shift, __bf16* __restrict__ oh,
                     __bf16* __restrict__ ol) {
  const int grp = threadIdx.x >> 4;        // 16 node-groups per block
  const int lane = threadIdx.x & 15;       // 16 lanes x 8 bf16 = 128 feats
  const int node = blockIdx.x * 16 + grp;
  if (node >= NN) return;
  int s = rowptr[node], e = rowptr[node + 1];
  // self term: hi + lo (fp32-exact reconstruction)
  bf16x8 sh8 = *(const bf16x8*)&yh[(long)node * 128 + lane * 8];
  bf16x8 sl8 = *(const bf16x8*)&yl[(long)node * 128 + lane * 8];
  float a[8], b[8];
#pragma unroll
  for (int j = 0; j < 8; ++j) { a[j] = (float)sh8[j] + (float)sl8[j]; b[j] = 0.f; }
  int i = s;
  for (; i + 3 < e; i += 4) {
    int s0 = csr_src[i], s1 = csr_src[i + 1], s2 = csr_src[i + 2], s3 = csr_src[i + 3];
    bf16x8 v0 = *(const bf16x8*)&yh[(long)s0 * 128 + lane * 8];
    bf16x8 v1 = *(const bf16x8*)&yh[(long)s1 * 128 + lane * 8];
    bf16x8 v2 = *(const bf16x8*)&yh[(long)s2 * 128 + lane * 8];
    bf16x8 v3 = *(const bf16x8*)&yh[(long)s3 * 128 + lane * 8];
#pragma unroll
    for (int j = 0; j < 8; ++j) {
      a[j] += (float)v0[j]; b[j] += (float)v1[j];
      a[j] += (float)v2[j]; b[j] += (float)v3[j];
    }
  }
  for (; i < e; ++i) {
    int sn = csr_src[i];
    bf16x8 v = *(const bf16x8*)&yh[(long)sn * 128 + lane * 8];
#pragma unroll
    for (int j = 0; j < 8; ++j) a[j] += (float)v[j];
  }
  f32x4 sc0 = ((const f32x4*)scale)[lane * 2];
  f32x4 sc1 = ((const f32x4*)scale)[lane * 2 + 1];
  f32x4 sh0 = ((const f32x4*)shift)[lane * 2];
  f32x4 sh1 = ((const f32x4*)shift)[lane * 2 + 1];
  float sc[8] = {sc0.x, sc0.y, sc0.z, sc0.w, sc1.x, sc1.y, sc1.z, sc1.w};
  float sf[8] = {sh0.x, sh0.y, sh0.z, sh0.w, sh1.x, sh1.y, sh1.z, sh1.w};
  bf16x8 hv, lv;
#pragma unroll
  for (int j = 0; j < 8; ++j) {
    float o = fmaxf((a[j] + b[j]) * sc[j] + sf[j], 0.f);
    __bf16 h = (__bf16)o;
    hv[j] = h;
    lv[j] = (__bf16)(o - (float)h);
  }
  *(bf16x8*)&oh[(long)node * 128 + lane * 8] = hv;
  *(bf16x8*)&ol[(long)node * 128 + lane * 8] = lv;
}

// ---- pool with fused graph-bounds; hi-plane only --------------------------
__global__ __launch_bounds__(128)
void pool_mean_split(const __bf16* __restrict__ h0h, const __bf16* __restrict__ h0l,
                     const __bf16* __restrict__ h1h, const __bf16* __restrict__ h1l,
                     const __bf16* __restrict__ h2h, const __bf16* __restrict__ h2l,
                     const int* __restrict__ batch, float* __restrict__ pooled) {
  __shared__ int se[2];
  int layer = blockIdx.y;
  const __bf16* hh = (layer == 0) ? h0h : (layer == 1) ? h1h : h2h;
  int g = blockIdx.x, c = threadIdx.x;
  if (threadIdx.x < 2) {
    int target = g + (int)threadIdx.x;   // lower bound of batch >= target
    int lo = 0, hi = NN;
    while (lo < hi) {
      int mid = (lo + hi) >> 1;
      if (batch[mid] < target) lo = mid + 1; else hi = mid;
    }
    se[threadIdx.x] = lo;
  }
  __syncthreads();
  int s = se[0], e = se[1];
  float a0 = 0.f, a1 = 0.f, a2 = 0.f, a3 = 0.f;
  int i = s;
  for (; i + 3 < e; i += 4) {
    a0 += (float)hh[(long)i * 128 + c];
    a1 += (float)hh[(long)(i + 1) * 128 + c];
    a2 += (float)hh[(long)(i + 2) * 128 + c];
    a3 += (float)hh[(long)(i + 3) * 128 + c];
  }
  for (; i < e; ++i)
    a0 += (float)hh[(long)i * 128 + c];
  float acc = (a0 + a1) + (a2 + a3);
  pooled[g * 384 + layer * 128 + c] = acc / fmaxf((float)(e - s), 1.f);
}

__global__ __launch_bounds__(384)
void lin1_k(const float* __restrict__ pooled, const float* __restrict__ w,
            const float* __restrict__ b, float* __restrict__ z) {
  __shared__ float pr[384];
  int mrow = blockIdx.x, t = threadIdx.x;
  pr[t] = pooled[mrow * 384 + t];
  __syncthreads();
  float acc = b[t];
  for (int k = 0; k < 384; ++k) acc += pr[k] * w[k * 384 + t];
  z[mrow * 384 + t] = fmaxf(acc, 0.f);
}

__global__ __launch_bounds__(192)
void lin2_k(const float* __restrict__ z, const float* __restrict__ w,
            const float* __restrict__ b, float* __restrict__ out) {
  int idx = blockIdx.x * 192 + threadIdx.x;
  if (idx >= NG * 3) return;
  int mrow = idx / 3, j = idx % 3;
  float acc = b[j];
  for (int k = 0; k < 384; ++k) acc += z[mrow * 384 + k] * w[k * 3 + j];
  out[idx] = acc;
}

extern "C" void kernel_launch(void* const* d_in, const int* in_sizes, int n_in,
                              void* d_out, int out_size, void* d_ws, size_t ws_size,
                              hipStream_t stream) {
  const float* x = (const float*)d_in[0];
  const int* ei = (const int*)d_in[1];
  const int* batch = (const int*)d_in[2];
  const int* srcv = ei;
  const int* dstv = ei + NE;
  const float* cw1[3] = {(const float*)d_in[3], (const float*)d_in[11], (const float*)d_in[19]};
  const float* cb1[3] = {(const float*)d_in[4], (const float*)d_in[12], (const float*)d_in[20]};
  const float* cg[3]  = {(const float*)d_in[5], (const float*)d_in[13], (const float*)d_in[21]};
  const float* cbb[3] = {(const float*)d_in[6], (const float*)d_in[14], (const float*)d_in[22]};
  const float* cm[3]  = {(const float*)d_in[7], (const float*)d_in[15], (const float*)d_in[23]};
  const float* cv[3]  = {(const float*)d_in[8], (const float*)d_in[16], (const float*)d_in[24]};
  const float* cw2[3] = {(const float*)d_in[9], (const float*)d_in[17], (const float*)d_in[25]};
  const float* cb2[3] = {(const float*)d_in[10], (const float*)d_in[18], (const float*)d_in[26]};
  const float* lin1_w = (const float*)d_in[27];
  const float* lin1_b = (const float*)d_in[28];
  const float* lin2_w = (const float*)d_in[29];
  const float* lin2_b = (const float*)d_in[30];

  const size_t NNF = (size_t)NN * 128;        // 6.4M
  float* wsf = (float*)d_ws;
  __bf16* yh = (__bf16*)wsf;                   // y hi-plane, 6.4M bf16
  __bf16* yl = yh + NNF;                       // y lo-plane, 6.4M bf16
  __bf16* Xb = (__bf16*)(wsf + NNF);           // bf16 plane region (after y)
  __bf16* gh = Xb;                             // gather split out, 6.4M bf16
  __bf16* gl = Xb + (size_t)6400000;
  __bf16* hh[3], *hl[3];
  for (int c = 0; c < 3; ++c) {
    hh[c] = Xb + (size_t)12800000 + (size_t)c * 12800000;
    hl[c] = hh[c] + (size_t)6400000;
  }
  float* misc = wsf + NNF + (size_t)25600000;  // after plane region (51.2M bf16)
  float* pooled = misc;                        // 256*384
  float* z      = pooled + (size_t)NG * 384;
  float* scale  = z + (size_t)NG * 384;        // 384 (3 layers x 128)
  float* shift  = scale + 384;
  __bf16* whbuf = (__bf16*)(shift + 384);      // WTOTAL bf16 per plane
  __bf16* wlbuf = whbuf + (size_t)WTOTAL;
  int* rowptr   = (int*)(wlbuf + (size_t)WTOTAL);   // NN+1
  int* cursor   = rowptr + NN + 1;
  int* csr_src  = cursor + NN;
  int* bsum     = csr_src + NE;
  int* boff     = bsum + 32;

  // ---- build CSR (by dst) once ----
  hipMemsetAsync(rowptr, 0, (NN + 1) * sizeof(int), stream);
  deg_count<<<(NE + 255) / 256, 256, 0, stream>>>(dstv, rowptr, NE);
  scan_sums<<<SCAN_NB, 256, 0, stream>>>(rowptr, bsum);
  scan_offs<<<1, 64, 0, stream>>>(bsum, boff, rowptr);
  scan_final<<<SCAN_NB, 256, 0, stream>>>(boff, rowptr, cursor);
  scatter_csr<<<(NE + 255) / 256, 256, 0, stream>>>(srcv, dstv, cursor, csr_src, NE);

  // ---- pre-fold all weights + BN params (ONE launch) ----
  wprep_all<<<(WTOTAL + 255) / 256 + 1, 256, 0, stream>>>(
      cw1[0], cw1[1], cw1[2], cw2[0], cw2[1], cw2[2], whbuf, wlbuf,
      cb1[0], cg[0], cbb[0], cm[0], cv[0],
      cb1[1], cg[1], cbb[1], cm[1], cv[1],
      cb1[2], cg[2], cbb[2], cm[2], cv[2], scale, shift);

  const int w1off[3] = {WOFF_C1W1, WOFF_C2W1, WOFF_C3W1};
  const int w2off[3] = {WOFF_W2_1, WOFF_W2_2, WOFF_W2_3};
  const int ws_grid  = (NN + 127) / 128;       // 391
  const int bsp_grid = (NN + 63) / 64;         // 782
  for (int c = 0; c < 3; ++c) {
    const __bf16* w1h = whbuf + w1off[c];
    const __bf16* w1l = wlbuf + w1off[c];
    const __bf16* w2h = whbuf + w2off[c];
    const __bf16* w2l = wlbuf + w2off[c];
    if (c == 0)
      gemm_ws<false, false, true, true><<<ws_grid, 256, 0, stream>>>(
          x, nullptr, nullptr, w1h, w1l, nullptr, nullptr, yh, yl, NN, 513, 576);
    else
      gemm_bsp<false, false, true, false><<<bsp_grid, 512, 0, stream>>>(
          nullptr, hh[c - 1], hl[c - 1], w1h, w1l, nullptr, nullptr, yh, yl, NN, 128, 128);
    gather_bn_split<<<(NN + 15) / 16, 256, 0, stream>>>(
        yh, yl, rowptr, csr_src, scale + (size_t)c * 128, shift + (size_t)c * 128, gh, gl);
    gemm_bsp<true, true, true, false><<<bsp_grid, 512, 0, stream>>>(
        nullptr, gh, gl, w2h, w2l, cb2[c], nullptr, hh[c], hl[c], NN, 128, 128);
  }
  pool_mean_split<<<dim3(NG, 3), 128, 0, stream>>>(hh[0], hl[0], hh[1], hl[1], hh[2], hl[2],
                                                   batch, pooled);
  lin1_k<<<NG, 384, 0, stream>>>(pooled, lin1_w, lin1_b, z);
  lin2_k<<<4, 192, 0, stream>>>(z, lin2_w, lin2_b, (float*)d_out);
}